// Round 6
// baseline (1804.691 us; speedup 1.0000x reference)
//
#include <hip/hip_runtime.h>
#include <hip/hip_bf16.h>

#define NN 20000   // nodes
#define NE 320000  // edges
#define NB 64      // graphs
#define DIN 16
#define DE 8
#define HE 128
#define D 32
#define TST 8
#define S2S 12

typedef __attribute__((ext_vector_type(8))) short short8x;   // 8 bf16 = 4 VGPRs (MFMA A/B frag)
typedef __attribute__((ext_vector_type(4))) float f32x4;     // MFMA C/D frag

__device__ __forceinline__ float sigf(float x) { return 1.f / (1.f + expf(-x)); }

__device__ __forceinline__ void split_bf16(float x, unsigned short& hi, unsigned short& lo) {
    __hip_bfloat16 h = __float2bfloat16(x);
    hi = *(unsigned short*)&h;
    float r = x - __bfloat162float(h);
    __hip_bfloat16 l = __float2bfloat16(r);
    lo = *(unsigned short*)&l;
}

// XOR-swizzled element offset of an A-frag within a 1024-el k-row of Wt.
__device__ __forceinline__ int swz_off(int eidx, int quad, int tile) {
    const int u = eidx * 4 + quad;
    const int s = u ^ ((u >> 3) & 7);
    return tile * 512 + s * 8;
}

// -------- Wt[k][swz(f,d)] = We2[k][d*32+f] (k<128), row 128 = be2; hi/lo bf16
__global__ __launch_bounds__(256) void k_prep_w(
    const float* __restrict__ We2, const float* __restrict__ be2,
    unsigned short* __restrict__ wth, unsigned short* __restrict__ wtl) {
    int idx = blockIdx.x * 256 + threadIdx.x;
    if (idx >= 129 * 1024) return;
    int k = idx >> 10, rem = idx & 1023, f = rem >> 5, d = rem & 31;
    float v = (k < 128) ? We2[k * 1024 + d * 32 + f] : be2[d * 32 + f];
    unsigned short hi, lo;
    split_bf16(v, hi, lo);
    const int pos = k * 1024 + swz_off(f & 15, d >> 3, f >> 4) + (d & 7);
    wth[pos] = hi;
    wtl[pos] = lo;
}

// -------- counting sort of edges by dst
__global__ __launch_bounds__(256) void k_hist(const int* __restrict__ dst, int* __restrict__ hist) {
    const int e = blockIdx.x * 256 + threadIdx.x;
    atomicAdd(&hist[dst[e]], 1);
}

__global__ __launch_bounds__(256) void k_scan(const int* __restrict__ hist, int* __restrict__ offs) {
    __shared__ int part[256];
    const int tid = threadIdx.x;
    const int base = tid * 79;  // 256*79 = 20224 >= NN
    int s = 0;
    for (int i = 0; i < 79; ++i) {
        const int b = base + i;
        if (b < NN) s += hist[b];
    }
    part[tid] = s;
    __syncthreads();
    if (tid == 0) {
        int a = 0;
        for (int i = 0; i < 256; ++i) { const int v = part[i]; part[i] = a; a += v; }
    }
    __syncthreads();
    int a = part[tid];
    for (int i = 0; i < 79; ++i) {
        const int b = base + i;
        if (b < NN) { offs[b] = a; a += hist[b]; }
    }
}

__global__ __launch_bounds__(256) void k_scatter(
    const int* __restrict__ src, const int* __restrict__ dst, const float* __restrict__ ed,
    int* __restrict__ offs, int* __restrict__ src_s, int* __restrict__ dst_s,
    float* __restrict__ ed_s) {
    const int e = blockIdx.x * 256 + threadIdx.x;
    const int d = dst[e];
    const int pos = atomicAdd(&offs[d], 1);
    src_s[pos] = src[e];
    dst_s[pos] = d;
    const float4 a = *(const float4*)(ed + (size_t)e * 8);
    const float4 b = *(const float4*)(ed + (size_t)e * 8 + 4);
    *(float4*)(ed_s + (size_t)pos * 8) = a;
    *(float4*)(ed_s + (size_t)pos * 8 + 4) = b;
}

// -------- h0 = x @ W_in + b_in  (+ optional bf16 hi/lo split emit)
__global__ __launch_bounds__(256) void k_input_linear(
    const float* __restrict__ x, const float* __restrict__ Win,
    const float* __restrict__ bin, float* __restrict__ h,
    unsigned short* __restrict__ hhi, unsigned short* __restrict__ hlo) {
    int idx = blockIdx.x * 256 + threadIdx.x;
    int n = idx >> 5, f = idx & 31;
    float acc = bin[f];
#pragma unroll
    for (int d = 0; d < DIN; ++d) acc += x[n * DIN + d] * Win[d * D + f];
    h[idx] = acc;
    if (hhi) {
        unsigned short hi, lo;
        split_bf16(acc, hi, lo);
        hhi[idx] = hi;
        hlo[idx] = lo;
    }
}

// -------- MFMA msg v16: ET=2 + ring-2 dataflow at the PROVEN (256,4) bound.
// Lesson from r1-r5: launch_bounds' 2nd arg is an allocator floor, not the
// occupancy lever -- runtime occupancy = floor(512/natural_alloc). v12's
// ET=4 dataflow naturally needs ~128 regs (64 arch + ~64 acc per CSV +
// occupancy arithmetic -> 4 waves/SIMD, 33%). This ET=2+ring2 dataflow
// needs ~80-95 naturally: at (256,4) the 128-reg budget guarantees ZERO
// spill, and if natural alloc lands <=85 we get 6 waves/SIMD, <=102 -> 5.
// Strictly no-worse than v12. Work totals unchanged (2x blocks x half
// work); z duplicated by upper half-wave (+~3% VALU); W L2 traffic 2x
// (L2-resident, trivial). Per-edge numerics identical (same k-order).
__global__ __launch_bounds__(256, 4) void k_msg_mfma16(
    const float* __restrict__ ed_s, const float* __restrict__ We1,
    const float* __restrict__ be1,
    const unsigned short* __restrict__ wth,
    const unsigned short* __restrict__ hhi,
    const int* __restrict__ src_s, const int* __restrict__ dst_s,
    float* __restrict__ agg) {
    const int tid = threadIdx.x;
    const int e0 = blockIdx.x * 128;

    __shared__ float msgb[128 * 17];  // 8704 B, epilogue only (2-pass over f)
    __shared__ float we1s[DE * HE];   // 4 KB
    __shared__ float be1s[HE];
    __shared__ int dsl[128];

    const int lane = tid & 63;
    const int wv = tid >> 6;
    const int eidx = lane & 15;
    const int quad = lane >> 4;
    const int d0 = quad * 8;
    const int swz0 = swz_off(eidx, quad, 0);
    const int swz1 = swz_off(eidx, quad, 1);

    for (int i = tid; i < DE * HE; i += 256) we1s[i] = We1[i];
    if (tid < HE) be1s[tid] = be1[tid];
    if (tid < 128) dsl[tid] = dst_s[e0 + tid];

    // per-lane edge row; lanes 32-63 duplicate lanes 0-31 (z redundantly computed)
    const int myeloc = wv * 32 + (lane & 31);
    const float4 ev0 = *(const float4*)(ed_s + (size_t)(e0 + myeloc) * 8);
    const float4 ev1 = *(const float4*)(ed_s + (size_t)(e0 + myeloc) * 8 + 4);
    float edr[8];
    edr[0] = ev0.x; edr[1] = ev0.y; edr[2] = ev0.z; edr[3] = ev0.w;
    edr[4] = ev1.x; edr[5] = ev1.y; edr[6] = ev1.z; edr[7] = ev1.w;

    // B-frags (h hi) for 2 e-tiles
    short8x bhi[2];
#pragma unroll
    for (int et = 0; et < 2; ++et) {
        const int e = e0 + wv * 32 + et * 16 + eidx;
        const size_t hb = (size_t)src_s[e] * 32 + d0;
        bhi[et] = *(const short8x*)(hhi + hb);
    }

    // 2-deep W-frag register ring (double buffer), direct from global (L2-hot)
    short8x ring[2][2];
#define LDW(slot, kk)                                                  \
    do {                                                               \
        const unsigned short* _p = wth + ((size_t)(kk) << 10);         \
        ring[slot][0] = *(const short8x*)(_p + swz0);                  \
        ring[slot][1] = *(const short8x*)(_p + swz1);                  \
    } while (0)
    LDW(0, 0);
    LDW(1, 1);

    f32x4 macc[2][2];
#pragma unroll
    for (int et = 0; et < 2; ++et) {
        macc[et][0] = (f32x4){0.f, 0.f, 0.f, 0.f};
        macc[et][1] = (f32x4){0.f, 0.f, 0.f, 0.f};
    }

    __syncthreads();  // we1s/be1s/dsl visible; ONLY barrier before epilogue

#pragma unroll 1
    for (int c = 0; c < 16; ++c) {
        // z for this chunk's 8 k, this lane's edge (exact fp32, same order)
        float zreg[8];
#pragma unroll
        for (int m = 0; m < 8; ++m) {
            const int k = c * 8 + m;
            float acc = be1s[k];
#pragma unroll
            for (int j = 0; j < 8; ++j) acc += edr[j] * we1s[j * HE + k];
            zreg[m] = fmaxf(acc, 0.f);
        }
#pragma unroll
        for (int m = 0; m < 8; ++m) {
            const int k = c * 8 + m;
            const int slot = m & 1;          // == k & 1 (8 ≡ 0 mod 2)

            float zk2[2];
#pragma unroll
            for (int et = 0; et < 2; ++et) zk2[et] = __shfl(zreg[m], et * 16 + eidx);

            const short8x fh0 = ring[slot][0];
            const short8x fh1 = ring[slot][1];
#pragma unroll
            for (int et = 0; et < 2; ++et) {
                f32x4 t0 = {0.f, 0.f, 0.f, 0.f};
                t0 = __builtin_amdgcn_mfma_f32_16x16x32_bf16(fh0, bhi[et], t0, 0, 0, 0);
                macc[et][0] += zk2[et] * t0;
            }
#pragma unroll
            for (int et = 0; et < 2; ++et) {
                f32x4 t1 = {0.f, 0.f, 0.f, 0.f};
                t1 = __builtin_amdgcn_mfma_f32_16x16x32_bf16(fh1, bhi[et], t1, 0, 0, 0);
                macc[et][1] += zk2[et] * t1;
            }

            // prefetch k+2 into the slot just consumed (used at iter k+2)
            int kn = k + 2;
            kn = (kn > 128) ? 128 : kn;
            LDW(slot, kn);
        }
    }

    {   // k = 128: be2 virtual row, z == 1; slot 0 holds k=128 (loaded @k=126)
        const short8x fh0 = ring[0][0];
        const short8x fh1 = ring[0][1];
#pragma unroll
        for (int et = 0; et < 2; ++et) {
            f32x4 t0 = {0.f, 0.f, 0.f, 0.f};
            t0 = __builtin_amdgcn_mfma_f32_16x16x32_bf16(fh0, bhi[et], t0, 0, 0, 0);
            macc[et][0] += t0;
            f32x4 t1 = {0.f, 0.f, 0.f, 0.f};
            t1 = __builtin_amdgcn_mfma_f32_16x16x32_bf16(fh1, bhi[et], t1, 0, 0, 0);
            macc[et][1] += t1;
        }
    }
#undef LDW

    // ---- epilogue pass 0: f 0..15 (macc[et][0]) ----
#pragma unroll
    for (int et = 0; et < 2; ++et) {
        const int eloc = wv * 32 + et * 16 + eidx;
        float* row = msgb + eloc * 17;
        row[quad * 4 + 0] = macc[et][0].x;
        row[quad * 4 + 1] = macc[et][0].y;
        row[quad * 4 + 2] = macc[et][0].z;
        row[quad * 4 + 3] = macc[et][0].w;
    }
    __syncthreads();
    {
        const int g = tid >> 4, fl = tid & 15;  // 16 groups x 8 edges, f = fl
        const int base = g * 8;
        float acc = 0.f;
        int cur = dsl[base];
        for (int i = 0; i < 8; ++i) {
            const int dnn = dsl[base + i];
            const float v = msgb[(base + i) * 17 + fl];
            if (dnn != cur) {
                atomicAdd(&agg[(size_t)cur * 32 + fl], acc);
                acc = 0.f;
                cur = dnn;
            }
            acc += v;
        }
        atomicAdd(&agg[(size_t)cur * 32 + fl], acc);
    }
    __syncthreads();  // pass-0 reads done before msgb reuse

    // ---- epilogue pass 1: f 16..31 (macc[et][1]) ----
#pragma unroll
    for (int et = 0; et < 2; ++et) {
        const int eloc = wv * 32 + et * 16 + eidx;
        float* row = msgb + eloc * 17;
        row[quad * 4 + 0] = macc[et][1].x;
        row[quad * 4 + 1] = macc[et][1].y;
        row[quad * 4 + 2] = macc[et][1].z;
        row[quad * 4 + 3] = macc[et][1].w;
    }
    __syncthreads();
    {
        const int g = tid >> 4, fl = tid & 15;  // f = 16 + fl
        const int base = g * 8;
        float acc = 0.f;
        int cur = dsl[base];
        for (int i = 0; i < 8; ++i) {
            const int dnn = dsl[base + i];
            const float v = msgb[(base + i) * 17 + fl];
            if (dnn != cur) {
                atomicAdd(&agg[(size_t)cur * 32 + 16 + fl], acc);
                acc = 0.f;
                cur = dnn;
            }
            acc += v;
        }
        atomicAdd(&agg[(size_t)cur * 32 + 16 + fl], acc);
    }
}

// -------- MFMA msg v2 (fallback, base ws only): ring prefetch, z in regs, 3-pass
#define LDFRAG(slot, kk)                                          \
    do {                                                          \
        const unsigned short* _ph = wth + ((size_t)(kk) << 10);   \
        const unsigned short* _pl = wtl + ((size_t)(kk) << 10);   \
        ring[slot][0] = *(const short8x*)(_ph + b0);              \
        ring[slot][1] = *(const short8x*)(_ph + b1);              \
        ring[slot][2] = *(const short8x*)(_pl + b0);              \
        ring[slot][3] = *(const short8x*)(_pl + b1);              \
    } while (0)

__global__ __launch_bounds__(256) void k_msg_mfma(
    const float* __restrict__ ed, const float* __restrict__ We1,
    const float* __restrict__ be1,
    const unsigned short* __restrict__ wth, const unsigned short* __restrict__ wtl,
    const unsigned short* __restrict__ hhi, const unsigned short* __restrict__ hlo,
    const int* __restrict__ src, const int* __restrict__ dst,
    float* __restrict__ agg) {
    const int tid = threadIdx.x;
    const int e0 = blockIdx.x * 64;

    __shared__ float we1s[DE * HE];
    __shared__ float be1s[HE];

    for (int i = tid; i < DE * HE; i += 256) we1s[i] = We1[i];
    if (tid < HE) be1s[tid] = be1[tid];

    const int lane = tid & 63;
    const int wv = tid >> 6;
    const int eidx = lane & 15;
    const int quad = lane >> 4;
    const int eloc = wv * 16 + eidx;
    const int e = e0 + eloc;
    const int d0 = quad * 8;

    const int sn = src[e];
    const int dn = dst[e];

    const int b0 = swz_off(eidx, quad, 0);
    const int b1 = swz_off(eidx, quad, 1);

    const size_t hb = (size_t)sn * 32 + d0;
    const short8x bhi = *(const short8x*)(hhi + hb);
    const short8x blo = *(const short8x*)(hlo + hb);
    const float4 edv0 = *(const float4*)(ed + (size_t)e * 8);
    const float4 edv1 = *(const float4*)(ed + (size_t)e * 8 + 4);

    short8x ring[4][4];
    LDFRAG(0, 0);
    LDFRAG(1, 1);
    LDFRAG(2, 2);

    __syncthreads();

    float edr[8];
    edr[0] = edv0.x; edr[1] = edv0.y; edr[2] = edv0.z; edr[3] = edv0.w;
    edr[4] = edv1.x; edr[5] = edv1.y; edr[6] = edv1.z; edr[7] = edv1.w;
    float zreg[32];
#pragma unroll
    for (int m = 0; m < 32; ++m) {
        const int kk = (quad << 5) + m;
        float acc = be1s[kk];
#pragma unroll
        for (int j = 0; j < 8; ++j) acc += edr[j] * we1s[j * 128 + kk];
        zreg[m] = fmaxf(acc, 0.f);
    }

    f32x4 m0 = {0.f, 0.f, 0.f, 0.f}, m1 = {0.f, 0.f, 0.f, 0.f};

    for (int q = 0; q < 4; ++q) {
        const int bsrc = q * 16 + eidx;
#pragma unroll
        for (int m = 0; m < 32; ++m) {
            const int k = q * 32 + m;
            const int slot = m & 3;
            const int pslot = (m + 3) & 3;
            int kn = k + 3;
            kn = (kn > 128) ? 128 : kn;
            LDFRAG(pslot, kn);

            const float zk = __shfl(zreg[m], bsrc);

            f32x4 t0 = {0.f, 0.f, 0.f, 0.f}, t1 = {0.f, 0.f, 0.f, 0.f};
            t0 = __builtin_amdgcn_mfma_f32_16x16x32_bf16(ring[slot][0], bhi, t0, 0, 0, 0);
            t1 = __builtin_amdgcn_mfma_f32_16x16x32_bf16(ring[slot][1], bhi, t1, 0, 0, 0);
            t0 = __builtin_amdgcn_mfma_f32_16x16x32_bf16(ring[slot][2], bhi, t0, 0, 0, 0);
            t1 = __builtin_amdgcn_mfma_f32_16x16x32_bf16(ring[slot][3], bhi, t1, 0, 0, 0);
            t0 = __builtin_amdgcn_mfma_f32_16x16x32_bf16(ring[slot][0], blo, t0, 0, 0, 0);
            t1 = __builtin_amdgcn_mfma_f32_16x16x32_bf16(ring[slot][1], blo, t1, 0, 0, 0);

            m0 += zk * t0;
            m1 += zk * t1;
        }
    }
    {
        f32x4 t0 = {0.f, 0.f, 0.f, 0.f}, t1 = {0.f, 0.f, 0.f, 0.f};
        t0 = __builtin_amdgcn_mfma_f32_16x16x32_bf16(ring[0][0], bhi, t0, 0, 0, 0);
        t1 = __builtin_amdgcn_mfma_f32_16x16x32_bf16(ring[0][1], bhi, t1, 0, 0, 0);
        t0 = __builtin_amdgcn_mfma_f32_16x16x32_bf16(ring[0][2], bhi, t0, 0, 0, 0);
        t1 = __builtin_amdgcn_mfma_f32_16x16x32_bf16(ring[0][3], bhi, t1, 0, 0, 0);
        t0 = __builtin_amdgcn_mfma_f32_16x16x32_bf16(ring[0][0], blo, t0, 0, 0, 0);
        t1 = __builtin_amdgcn_mfma_f32_16x16x32_bf16(ring[0][1], blo, t1, 0, 0, 0);
        m0 += t0;
        m1 += t1;
    }

    float* ap = agg + (size_t)dn * 32 + quad * 4;
    atomicAdd(ap + 0, m0.x);
    atomicAdd(ap + 1, m0.y);
    atomicAdd(ap + 2, m0.z);
    atomicAdd(ap + 3, m0.w);
    atomicAdd(ap + 16 + 0, m1.x);
    atomicAdd(ap + 16 + 1, m1.y);
    atomicAdd(ap + 16 + 2, m1.z);
    atomicAdd(ap + 16 + 3, m1.w);
}

// -------- fallback (proven R2 path): recompute z per edge, fp32 VALU bilinear
__global__ __launch_bounds__(256) void k_msg_fused(
    const float* __restrict__ ed, const float* __restrict__ We1,
    const float* __restrict__ be1, const float* __restrict__ We2,
    const float* __restrict__ h, const int* __restrict__ src,
    const int* __restrict__ dst, float* __restrict__ agg) {
    const int tid = threadIdx.x;
    const int e0 = blockIdx.x * 64;
    __shared__ float we1s[DE * HE];
    __shared__ float be1s[HE];
    __shared__ float eds[64][9];
    __shared__ float zs[HE][64];
    __shared__ float hs[64][33];
    __shared__ float ws2s[4][1024];
    __shared__ int srcs[64];

    for (int i = tid; i < DE * HE; i += 256) we1s[i] = We1[i];
    if (tid < HE) be1s[tid] = be1[tid];
    if (tid < 64) srcs[tid] = src[e0 + tid];
    for (int i = tid; i < 64 * DE; i += 256) eds[i >> 3][i & 7] = ed[(size_t)e0 * DE + i];
    __syncthreads();

    {
        const int e = tid & 63, kb = tid >> 6;
        float edr[8];
#pragma unroll
        for (int j = 0; j < 8; ++j) edr[j] = eds[e][j];
        for (int m = 0; m < 32; ++m) {
            const int k = kb * 32 + m;
            float acc = be1s[k];
#pragma unroll
            for (int j = 0; j < 8; ++j) acc += edr[j] * we1s[j * HE + k];
            zs[k][e] = fmaxf(acc, 0.f);
        }
    }
    for (int i = tid; i < 64 * 32; i += 256) {
        const int e = i >> 5, d = i & 31;
        hs[e][d] = h[(size_t)srcs[e] * D + d];
    }
    __syncthreads();

    const int ep = tid & 31, fg = tid >> 5;
    float hr[2][32];
#pragma unroll
    for (int d = 0; d < 32; ++d) {
        hr[0][d] = hs[ep * 2][d];
        hr[1][d] = hs[ep * 2 + 1][d];
    }
    float acc[2][4];
#pragma unroll
    for (int i = 0; i < 2; ++i)
#pragma unroll
        for (int j = 0; j < 4; ++j) acc[i][j] = 0.f;

    for (int kc = 0; kc < 32; ++kc) {
        __syncthreads();
#pragma unroll
        for (int r = 0; r < 4; ++r) {
            const int idx4 = tid + 256 * r;
            const int kr = idx4 >> 8, c4 = idx4 & 255;
            *(float4*)&ws2s[kr][c4 * 4] =
                *(const float4*)(We2 + (size_t)(kc * 4 + kr) * 1024 + c4 * 4);
        }
        __syncthreads();
#pragma unroll
        for (int kk = 0; kk < 4; ++kk) {
            const int k = kc * 4 + kk;
            const float z0 = zs[k][ep * 2], z1 = zs[k][ep * 2 + 1];
#pragma unroll
            for (int d = 0; d < 32; ++d) {
                const float4 w4 = *(const float4*)&ws2s[kk][d * 32 + fg * 4];
                const float c0 = z0 * hr[0][d], c1 = z1 * hr[1][d];
                acc[0][0] += c0 * w4.x; acc[0][1] += c0 * w4.y;
                acc[0][2] += c0 * w4.z; acc[0][3] += c0 * w4.w;
                acc[1][0] += c1 * w4.x; acc[1][1] += c1 * w4.y;
                acc[1][2] += c1 * w4.z; acc[1][3] += c1 * w4.w;
            }
        }
    }
#pragma unroll
    for (int i = 0; i < 2; ++i) {
        const int e = e0 + ep * 2 + i;
        float* ap = &agg[(size_t)dst[e] * D + fg * 4];
#pragma unroll
        for (int j = 0; j < 4; ++j) atomicAdd(ap + j, acc[i][j]);
    }
}

// -------- GRU cell per node; reads agg then re-zeroes it (replaces memsets)
__global__ __launch_bounds__(256) void k_gru(
    const float* __restrict__ h, float* __restrict__ agg,
    const float* __restrict__ Wroot, const float* __restrict__ bconv,
    const float* __restrict__ Wih, const float* __restrict__ Whh,
    const float* __restrict__ bih, const float* __restrict__ bhh,
    float* __restrict__ hout,
    unsigned short* __restrict__ hhi, unsigned short* __restrict__ hlo) {
    const int idx = blockIdx.x * 256 + threadIdx.x;
    const int n = idx >> 5, f = idx & 31, nl = threadIdx.x >> 5;
    __shared__ float hsh[8][33], msh[8][33];
    const float hv = h[n * D + f];
    hsh[nl][f] = hv;
    __syncthreads();
    float m = bconv[f] + agg[n * D + f];
    agg[n * D + f] = 0.f;  // re-zero for next msg step
#pragma unroll
    for (int d = 0; d < 32; ++d) m += hsh[nl][d] * Wroot[d * D + f];
    m = fmaxf(m, 0.f);
    msh[nl][f] = m;
    __syncthreads();
    float gir = bih[f], giz = bih[D + f], gin = bih[2 * D + f];
    float ghr = bhh[f], ghz = bhh[D + f], ghn = bhh[2 * D + f];
#pragma unroll
    for (int d = 0; d < 32; ++d) {
        const float md = msh[nl][d], hd = hsh[nl][d];
        gir += md * Wih[f * D + d];
        giz += md * Wih[(D + f) * D + d];
        gin += md * Wih[(2 * D + f) * D + d];
        ghr += hd * Whh[f * D + d];
        ghz += hd * Whh[(D + f) * D + d];
        ghn += hd * Whh[(2 * D + f) * D + d];
    }
    const float r = sigf(gir + ghr);
    const float z = sigf(giz + ghz);
    const float nn2 = tanhf(gin + r * ghn);
    const float ho = (1.f - z) * nn2 + z * hv;
    hout[n * D + f] = ho;
    if (hhi) {
        unsigned short hi, lo;
        split_bf16(ho, hi, lo);
        hhi[idx] = hi;
        hlo[idx] = lo;
    }
}

// -------- all 12 Set2Set steps + output head in ONE kernel: block = graph
__global__ __launch_bounds__(256) void k_s2s_all(
    const float* __restrict__ h, const int* __restrict__ batch,
    const float* __restrict__ Wih, const float* __restrict__ Whh,
    const float* __restrict__ bih, const float* __restrict__ bhh,
    const float* __restrict__ Wout, const float* __restrict__ bout,
    float* __restrict__ ebuf, float* __restrict__ out) {
    const int b = blockIdx.x, t = threadIdx.x;
    __shared__ float qst[64], hls[32], cls[32], gates[128], qs[32];
    __shared__ float red[256];
    __shared__ float rsum[8][33];
    __shared__ int sse[2];
    if (t < 64) qst[t] = 0.f;
    if (t < 32) { hls[t] = 0.f; cls[t] = 0.f; }
    if (t < 2) {  // own graph segment via binary search on sorted batch
        const int target = b + t;
        int lo = 0, hi = NN;
        while (lo < hi) {
            int mid = (lo + hi) >> 1;
            if (batch[mid] < target) lo = mid + 1; else hi = mid;
        }
        sse[t] = lo;
    }
    __syncthreads();
    const int s0 = sse[0], s1 = sse[1];

    for (int s = 0; s < S2S; ++s) {
        if (t < 128) {
            float g = bih[t] + bhh[t];
#pragma unroll 8
            for (int j = 0; j < 64; ++j) g += qst[j] * Wih[t * 64 + j];
#pragma unroll 8
            for (int j = 0; j < 32; ++j) g += hls[j] * Whh[t * 32 + j];
            gates[t] = g;
        }
        __syncthreads();
        if (t < 32) {  // i,f,g,o order
            const float ig = sigf(gates[t]);
            const float fg = sigf(gates[32 + t]);
            const float gg = tanhf(gates[64 + t]);
            const float og = sigf(gates[96 + t]);
            const float c = fg * cls[t] + ig * gg;
            const float q = og * tanhf(c);
            cls[t] = c;
            hls[t] = q;
            qst[t] = q;
            qs[t] = q;
        }
        __syncthreads();
        float lmax = -3.4e38f;
        for (int n = s0 + t; n < s1; n += 256) {
            const float4* hv = (const float4*)(h + (size_t)n * D);
            float e = 0.f;
#pragma unroll
            for (int u = 0; u < 8; ++u) {
                const float4 v = hv[u];
                e += v.x * qs[u * 4] + v.y * qs[u * 4 + 1] + v.z * qs[u * 4 + 2] + v.w * qs[u * 4 + 3];
            }
            ebuf[n] = e;
            lmax = fmaxf(lmax, e);
        }
        red[t] = lmax;
        __syncthreads();
        for (int r2 = 128; r2 > 0; r2 >>= 1) {
            if (t < r2) red[t] = fmaxf(red[t], red[t + r2]);
            __syncthreads();
        }
        const float smax = red[0];
        __syncthreads();
        float lsum = 0.f;
        for (int n = s0 + t; n < s1; n += 256) {
            const float w = expf(ebuf[n] - smax);
            ebuf[n] = w;
            lsum += w;
        }
        red[t] = lsum;
        __syncthreads();
        for (int r2 = 128; r2 > 0; r2 >>= 1) {
            if (t < r2) red[t] += red[t + r2];
            __syncthreads();
        }
        const float den = red[0];
        const float inv = (den > 0.f) ? 1.f / den : 0.f;
        const int fl = t & 31, sl = t >> 5;
        float racc = 0.f;
        for (int n = s0 + sl; n < s1; n += 8) racc += ebuf[n] * h[(size_t)n * D + fl];
        rsum[sl][fl] = racc;
        __syncthreads();
        if (sl == 0) {
            float rv = 0.f;
#pragma unroll
            for (int u = 0; u < 8; ++u) rv += rsum[u][fl];
            qst[32 + fl] = rv * inv;
        }
        __syncthreads();  // qst[32..63] visible before next gates phase
    }

    if (t == 0) {  // fused output head
        float acc = bout[0];
#pragma unroll 8
        for (int j = 0; j < 64; ++j) acc += qst[j] * Wout[j];
        out[b] = acc;
    }
}

extern "C" void kernel_launch(void* const* d_in, const int* in_sizes, int n_in,
                              void* d_out, int out_size, void* d_ws, size_t ws_size,
                              hipStream_t stream) {
    const float* x     = (const float*)d_in[0];
    const float* ed    = (const float*)d_in[3];
    const int*   edges = (const int*)d_in[4];
    const int*   batch = (const int*)d_in[5];
    const float* Wi    = (const float*)d_in[6];
    const float* bi    = (const float*)d_in[7];
    const float* We1   = (const float*)d_in[8];
    const float* be1   = (const float*)d_in[9];
    const float* We2   = (const float*)d_in[10];
    const float* be2   = (const float*)d_in[11];
    const float* Wroot = (const float*)d_in[12];
    const float* bconv = (const float*)d_in[13];
    const float* gWih  = (const float*)d_in[14];
    const float* gWhh  = (const float*)d_in[15];
    const float* gbih  = (const float*)d_in[16];
    const float* gbhh  = (const float*)d_in[17];
    const float* lWih  = (const float*)d_in[18];
    const float* lWhh  = (const float*)d_in[19];
    const float* lbih  = (const float*)d_in[20];
    const float* lbhh  = (const float*)d_in[21];
    const float* Wout  = (const float*)d_in[22];
    const float* bout  = (const float*)d_in[23];
    float* out = (float*)d_out;

    const int* srcp = edges;
    const int* dstp = edges + NE;

    char* ws = (char*)d_ws;
    size_t off = 0;
    auto alloc = [&](size_t bytes) -> char* {
        char* p = ws + off;
        off += (bytes + 255) & ~(size_t)255;
        return p;
    };
    float* hA    = (float*)alloc((size_t)NN * D * 4);
    float* hB    = (float*)alloc((size_t)NN * D * 4);
    float* agg   = (float*)alloc((size_t)NN * D * 4);
    float* ebuf  = (float*)alloc((size_t)NN * 4);
    unsigned short* hhiA = (unsigned short*)alloc((size_t)NN * D * 2);
    unsigned short* hloA = (unsigned short*)alloc((size_t)NN * D * 2);
    unsigned short* hhiB = (unsigned short*)alloc((size_t)NN * D * 2);
    unsigned short* hloB = (unsigned short*)alloc((size_t)NN * D * 2);
    unsigned short* wth  = (unsigned short*)alloc((size_t)129 * 1024 * 2);
    unsigned short* wtl  = (unsigned short*)alloc((size_t)129 * 1024 * 2);
    const size_t base_off = off;
    const bool mfma_path = (ws_size >= base_off);
    // sorted-edge extras (~14 MB)
    int*   hist  = (int*)alloc((size_t)NN * 4);
    int*   offs  = (int*)alloc((size_t)NN * 4);
    int*   src_s = (int*)alloc((size_t)NE * 4);
    int*   dst_s = (int*)alloc((size_t)NE * 4);
    float* ed_s  = (float*)alloc((size_t)NE * 8 * 4);
    const bool mfma10_path = (ws_size >= off);

    hipLaunchKernelGGL(k_input_linear, dim3(NN * D / 256), dim3(256), 0, stream, x, Wi, bi, hA,
                       mfma_path ? hhiA : (unsigned short*)nullptr,
                       mfma_path ? hloA : (unsigned short*)nullptr);
    if (mfma_path)
        hipLaunchKernelGGL(k_prep_w, dim3((129 * 1024 + 255) / 256), dim3(256), 0, stream,
                           We2, be2, wth, wtl);
    if (mfma10_path) {
        hipMemsetAsync(hist, 0, (size_t)NN * 4, stream);
        hipLaunchKernelGGL(k_hist, dim3(NE / 256), dim3(256), 0, stream, dstp, hist);
        hipLaunchKernelGGL(k_scan, dim3(1), dim3(256), 0, stream, hist, offs);
        hipLaunchKernelGGL(k_scatter, dim3(NE / 256), dim3(256), 0, stream,
                           srcp, dstp, ed, offs, src_s, dst_s, ed_s);
    }
    hipMemsetAsync(agg, 0, (size_t)NN * D * 4, stream);  // once; k_gru re-zeroes

    float* hcur = hA;
    float* hnxt = hB;
    unsigned short *hhic = hhiA, *hloc = hloA, *hhin = hhiB, *hlon = hloB;
    for (int t = 0; t < TST; ++t) {
        if (mfma10_path)
            hipLaunchKernelGGL(k_msg_mfma16, dim3(NE / 128), dim3(256), 0, stream,
                               ed_s, We1, be1, wth, hhic, src_s, dst_s, agg);
        else if (mfma_path)
            hipLaunchKernelGGL(k_msg_mfma, dim3(NE / 64), dim3(256), 0, stream,
                               ed, We1, be1, wth, wtl, hhic, hloc, srcp, dstp, agg);
        else
            hipLaunchKernelGGL(k_msg_fused, dim3(NE / 64), dim3(256), 0, stream,
                               ed, We1, be1, We2, hcur, srcp, dstp, agg);
        hipLaunchKernelGGL(k_gru, dim3(NN * D / 256), dim3(256), 0, stream,
                           hcur, agg, Wroot, bconv, gWih, gWhh, gbih, gbhh, hnxt,
                           mfma_path ? hhin : (unsigned short*)nullptr,
                           mfma_path ? hlon : (unsigned short*)nullptr);
        float* tf = hcur; hcur = hnxt; hnxt = tf;
        unsigned short* ts;
        ts = hhic; hhic = hhin; hhin = ts;
        ts = hloc; hloc = hlon; hlon = ts;
    }

    hipLaunchKernelGGL(k_s2s_all, dim3(NB), dim3(256), 0, stream,
                       hcur, batch, lWih, lWhh, lbih, lbhh, Wout, bout, ebuf, out);
    (void)in_sizes; (void)n_in; (void)out_size;
}

// Round 7
// 1727.738 us; speedup vs baseline: 1.0445x; 1.0445x over previous
//
#include <hip/hip_runtime.h>
#include <hip/hip_bf16.h>

#define NN 20000   // nodes
#define NE 320000  // edges
#define NB 64      // graphs
#define DIN 16
#define DE 8
#define HE 128
#define D 32
#define TST 8
#define S2S 12

typedef __attribute__((ext_vector_type(8))) short short8x;   // 8 bf16 = 4 VGPRs (MFMA A/B frag)
typedef __attribute__((ext_vector_type(4))) float f32x4;     // MFMA C/D frag

__device__ __forceinline__ float sigf(float x) { return 1.f / (1.f + expf(-x)); }

__device__ __forceinline__ void split_bf16(float x, unsigned short& hi, unsigned short& lo) {
    __hip_bfloat16 h = __float2bfloat16(x);
    hi = *(unsigned short*)&h;
    float r = x - __bfloat162float(h);
    __hip_bfloat16 l = __float2bfloat16(r);
    lo = *(unsigned short*)&l;
}

// XOR-swizzled element offset of an A-frag within a 1024-el k-row of Wt.
__device__ __forceinline__ int swz_off(int eidx, int quad, int tile) {
    const int u = eidx * 4 + quad;
    const int s = u ^ ((u >> 3) & 7);
    return tile * 512 + s * 8;
}

// -------- Wt[k][swz(f,d)] = We2[k][d*32+f] (k<128), row 128 = be2; hi/lo bf16
__global__ __launch_bounds__(256) void k_prep_w(
    const float* __restrict__ We2, const float* __restrict__ be2,
    unsigned short* __restrict__ wth, unsigned short* __restrict__ wtl) {
    int idx = blockIdx.x * 256 + threadIdx.x;
    if (idx >= 129 * 1024) return;
    int k = idx >> 10, rem = idx & 1023, f = rem >> 5, d = rem & 31;
    float v = (k < 128) ? We2[k * 1024 + d * 32 + f] : be2[d * 32 + f];
    unsigned short hi, lo;
    split_bf16(v, hi, lo);
    const int pos = k * 1024 + swz_off(f & 15, d >> 3, f >> 4) + (d & 7);
    wth[pos] = hi;
    wtl[pos] = lo;
}

// -------- counting sort of edges by dst
__global__ __launch_bounds__(256) void k_hist(const int* __restrict__ dst, int* __restrict__ hist) {
    const int e = blockIdx.x * 256 + threadIdx.x;
    atomicAdd(&hist[dst[e]], 1);
}

__global__ __launch_bounds__(256) void k_scan(const int* __restrict__ hist, int* __restrict__ offs) {
    __shared__ int part[256];
    const int tid = threadIdx.x;
    const int base = tid * 79;  // 256*79 = 20224 >= NN
    int s = 0;
    for (int i = 0; i < 79; ++i) {
        const int b = base + i;
        if (b < NN) s += hist[b];
    }
    part[tid] = s;
    __syncthreads();
    if (tid == 0) {
        int a = 0;
        for (int i = 0; i < 256; ++i) { const int v = part[i]; part[i] = a; a += v; }
    }
    __syncthreads();
    int a = part[tid];
    for (int i = 0; i < 79; ++i) {
        const int b = base + i;
        if (b < NN) { offs[b] = a; a += hist[b]; }
    }
}

__global__ __launch_bounds__(256) void k_scatter(
    const int* __restrict__ src, const int* __restrict__ dst, const float* __restrict__ ed,
    int* __restrict__ offs, int* __restrict__ src_s, int* __restrict__ dst_s,
    float* __restrict__ ed_s) {
    const int e = blockIdx.x * 256 + threadIdx.x;
    const int d = dst[e];
    const int pos = atomicAdd(&offs[d], 1);
    src_s[pos] = src[e];
    dst_s[pos] = d;
    const float4 a = *(const float4*)(ed + (size_t)e * 8);
    const float4 b = *(const float4*)(ed + (size_t)e * 8 + 4);
    *(float4*)(ed_s + (size_t)pos * 8) = a;
    *(float4*)(ed_s + (size_t)pos * 8 + 4) = b;
}

// -------- h0 = x @ W_in + b_in  (+ optional bf16 hi/lo split emit)
__global__ __launch_bounds__(256) void k_input_linear(
    const float* __restrict__ x, const float* __restrict__ Win,
    const float* __restrict__ bin, float* __restrict__ h,
    unsigned short* __restrict__ hhi, unsigned short* __restrict__ hlo) {
    int idx = blockIdx.x * 256 + threadIdx.x;
    int n = idx >> 5, f = idx & 31;
    float acc = bin[f];
#pragma unroll
    for (int d = 0; d < DIN; ++d) acc += x[n * DIN + d] * Win[d * D + f];
    h[idx] = acc;
    if (hhi) {
        unsigned short hi, lo;
        split_bf16(acc, hi, lo);
        hhi[idx] = hi;
        hlo[idx] = lo;
    }
}

// -------- MFMA msg v17 body: ET=2 + ring-2 (HW-verified in v16) + z-PARITY
// split fixing v16's z duplication: lanes 0-31 compute z only for EVEN k's
// of their edge, lanes 32-63 only for ODD k's (zreg 8->4 regs, z work back
// to v12's 1x). Consumer shfl: zk for k=c*8+m of tile et comes from lane
// (m&1)*32 + et*16 + eidx, whose zreg[m>>1] holds exactly that k, computed
// in the same fp32 order -> numerics identical. Est footprint ~68 unified
// regs; stamped at (256,6) [85-reg budget] and (256,5) [102] as NON-template
// kernels (r5 lesson: hipFuncGetAttributes on template-kernel addresses can
// fail -> gate silently falls back). Cascade 6 -> 5 -> v12.
__device__ __forceinline__ void msg17_body(
    const float* __restrict__ ed_s, const float* __restrict__ We1,
    const float* __restrict__ be1,
    const unsigned short* __restrict__ wth,
    const unsigned short* __restrict__ hhi,
    const int* __restrict__ src_s, const int* __restrict__ dst_s,
    float* __restrict__ agg) {
    const int tid = threadIdx.x;
    const int e0 = blockIdx.x * 128;

    __shared__ float msgb[128 * 17];  // 8704 B, epilogue only (2-pass over f)
    __shared__ float we1s[DE * HE];   // 4 KB
    __shared__ float be1s[HE];
    __shared__ int dsl[128];

    const int lane = tid & 63;
    const int wv = tid >> 6;
    const int eidx = lane & 15;
    const int quad = lane >> 4;
    const int d0 = quad * 8;
    const int zpar = lane >> 5;       // z parity owned by this half-wave
    const int swz0 = swz_off(eidx, quad, 0);
    const int swz1 = swz_off(eidx, quad, 1);

    for (int i = tid; i < DE * HE; i += 256) we1s[i] = We1[i];
    if (tid < HE) be1s[tid] = be1[tid];
    if (tid < 128) dsl[tid] = dst_s[e0 + tid];

    // per-lane edge row; both half-waves hold the same edge's row
    const int myeloc = wv * 32 + (lane & 31);
    const float4 ev0 = *(const float4*)(ed_s + (size_t)(e0 + myeloc) * 8);
    const float4 ev1 = *(const float4*)(ed_s + (size_t)(e0 + myeloc) * 8 + 4);
    float edr[8];
    edr[0] = ev0.x; edr[1] = ev0.y; edr[2] = ev0.z; edr[3] = ev0.w;
    edr[4] = ev1.x; edr[5] = ev1.y; edr[6] = ev1.z; edr[7] = ev1.w;

    // B-frags (h hi) for 2 e-tiles
    short8x bhi[2];
#pragma unroll
    for (int et = 0; et < 2; ++et) {
        const int e = e0 + wv * 32 + et * 16 + eidx;
        const size_t hb = (size_t)src_s[e] * 32 + d0;
        bhi[et] = *(const short8x*)(hhi + hb);
    }

    // 2-deep W-frag register ring (double buffer), direct from global (L2-hot)
    short8x ring[2][2];
#define LDW17(slot, kk)                                                \
    do {                                                               \
        const unsigned short* _p = wth + ((size_t)(kk) << 10);         \
        ring[slot][0] = *(const short8x*)(_p + swz0);                  \
        ring[slot][1] = *(const short8x*)(_p + swz1);                  \
    } while (0)
    LDW17(0, 0);
    LDW17(1, 1);

    f32x4 macc[2][2];
#pragma unroll
    for (int et = 0; et < 2; ++et) {
        macc[et][0] = (f32x4){0.f, 0.f, 0.f, 0.f};
        macc[et][1] = (f32x4){0.f, 0.f, 0.f, 0.f};
    }

    __syncthreads();  // we1s/be1s/dsl visible; ONLY barrier before epilogue

#pragma unroll 1
    for (int c = 0; c < 16; ++c) {
        // z for this half-wave's 4 k's (k = c*8 + 2t + zpar), exact fp32 order
        float zreg[4];
#pragma unroll
        for (int t = 0; t < 4; ++t) {
            const int k = c * 8 + t * 2 + zpar;
            float acc = be1s[k];
#pragma unroll
            for (int j = 0; j < 8; ++j) acc += edr[j] * we1s[j * HE + k];
            zreg[t] = fmaxf(acc, 0.f);
        }
#pragma unroll
        for (int m = 0; m < 8; ++m) {
            const int k = c * 8 + m;
            const int slot = m & 1;          // == k & 1 (8 ≡ 0 mod 2)
            const int pm = m & 1;            // parity of this k
            const int tz = m >> 1;           // zreg slot at source lane

            float zk2[2];
#pragma unroll
            for (int et = 0; et < 2; ++et)
                zk2[et] = __shfl(zreg[tz], pm * 32 + et * 16 + eidx);

            const short8x fh0 = ring[slot][0];
            const short8x fh1 = ring[slot][1];
#pragma unroll
            for (int et = 0; et < 2; ++et) {
                f32x4 t0 = {0.f, 0.f, 0.f, 0.f};
                t0 = __builtin_amdgcn_mfma_f32_16x16x32_bf16(fh0, bhi[et], t0, 0, 0, 0);
                macc[et][0] += zk2[et] * t0;
            }
#pragma unroll
            for (int et = 0; et < 2; ++et) {
                f32x4 t1 = {0.f, 0.f, 0.f, 0.f};
                t1 = __builtin_amdgcn_mfma_f32_16x16x32_bf16(fh1, bhi[et], t1, 0, 0, 0);
                macc[et][1] += zk2[et] * t1;
            }

            // prefetch k+2 into the slot just consumed (used at iter k+2)
            int kn = k + 2;
            kn = (kn > 128) ? 128 : kn;
            LDW17(slot, kn);
        }
    }

    {   // k = 128: be2 virtual row, z == 1; slot 0 holds k=128 (loaded @k=126)
        const short8x fh0 = ring[0][0];
        const short8x fh1 = ring[0][1];
#pragma unroll
        for (int et = 0; et < 2; ++et) {
            f32x4 t0 = {0.f, 0.f, 0.f, 0.f};
            t0 = __builtin_amdgcn_mfma_f32_16x16x32_bf16(fh0, bhi[et], t0, 0, 0, 0);
            macc[et][0] += t0;
            f32x4 t1 = {0.f, 0.f, 0.f, 0.f};
            t1 = __builtin_amdgcn_mfma_f32_16x16x32_bf16(fh1, bhi[et], t1, 0, 0, 0);
            macc[et][1] += t1;
        }
    }
#undef LDW17

    // ---- epilogue pass 0: f 0..15 (macc[et][0]) ----
#pragma unroll
    for (int et = 0; et < 2; ++et) {
        const int eloc = wv * 32 + et * 16 + eidx;
        float* row = msgb + eloc * 17;
        row[quad * 4 + 0] = macc[et][0].x;
        row[quad * 4 + 1] = macc[et][0].y;
        row[quad * 4 + 2] = macc[et][0].z;
        row[quad * 4 + 3] = macc[et][0].w;
    }
    __syncthreads();
    {
        const int g = tid >> 4, fl = tid & 15;  // 16 groups x 8 edges, f = fl
        const int base = g * 8;
        float acc = 0.f;
        int cur = dsl[base];
        for (int i = 0; i < 8; ++i) {
            const int dnn = dsl[base + i];
            const float v = msgb[(base + i) * 17 + fl];
            if (dnn != cur) {
                atomicAdd(&agg[(size_t)cur * 32 + fl], acc);
                acc = 0.f;
                cur = dnn;
            }
            acc += v;
        }
        atomicAdd(&agg[(size_t)cur * 32 + fl], acc);
    }
    __syncthreads();  // pass-0 reads done before msgb reuse

    // ---- epilogue pass 1: f 16..31 (macc[et][1]) ----
#pragma unroll
    for (int et = 0; et < 2; ++et) {
        const int eloc = wv * 32 + et * 16 + eidx;
        float* row = msgb + eloc * 17;
        row[quad * 4 + 0] = macc[et][1].x;
        row[quad * 4 + 1] = macc[et][1].y;
        row[quad * 4 + 2] = macc[et][1].z;
        row[quad * 4 + 3] = macc[et][1].w;
    }
    __syncthreads();
    {
        const int g = tid >> 4, fl = tid & 15;  // f = 16 + fl
        const int base = g * 8;
        float acc = 0.f;
        int cur = dsl[base];
        for (int i = 0; i < 8; ++i) {
            const int dnn = dsl[base + i];
            const float v = msgb[(base + i) * 17 + fl];
            if (dnn != cur) {
                atomicAdd(&agg[(size_t)cur * 32 + 16 + fl], acc);
                acc = 0.f;
                cur = dnn;
            }
            acc += v;
        }
        atomicAdd(&agg[(size_t)cur * 32 + 16 + fl], acc);
    }
}

__global__ __launch_bounds__(256, 6) void k_msg_mfma17_w6(
    const float* __restrict__ ed_s, const float* __restrict__ We1,
    const float* __restrict__ be1, const unsigned short* __restrict__ wth,
    const unsigned short* __restrict__ hhi,
    const int* __restrict__ src_s, const int* __restrict__ dst_s,
    float* __restrict__ agg) {
    msg17_body(ed_s, We1, be1, wth, hhi, src_s, dst_s, agg);
}

__global__ __launch_bounds__(256, 5) void k_msg_mfma17_w5(
    const float* __restrict__ ed_s, const float* __restrict__ We1,
    const float* __restrict__ be1, const unsigned short* __restrict__ wth,
    const unsigned short* __restrict__ hhi,
    const int* __restrict__ src_s, const int* __restrict__ dst_s,
    float* __restrict__ agg) {
    msg17_body(ed_s, We1, be1, wth, hhi, src_s, dst_s, agg);
}

// -------- MFMA msg v12 (proven fallback): 2-pass epilogue, (256,4)
__global__ __launch_bounds__(256, 4) void k_msg_mfma10(
    const float* __restrict__ ed_s, const float* __restrict__ We1,
    const float* __restrict__ be1,
    const unsigned short* __restrict__ wth,
    const unsigned short* __restrict__ hhi,
    const int* __restrict__ src_s, const int* __restrict__ dst_s,
    float* __restrict__ agg) {
    const int tid = threadIdx.x;
    const int e0 = blockIdx.x * 256;

    __shared__ float msgb[256 * 17];  // 17408 B, epilogue only (2-pass over f)
    __shared__ float we1s[DE * HE];   // 4 KB
    __shared__ float be1s[HE];
    __shared__ int dsl[256];

    const int lane = tid & 63;
    const int wv = tid >> 6;
    const int eidx = lane & 15;
    const int quad = lane >> 4;
    const int d0 = quad * 8;
    const int swz0 = swz_off(eidx, quad, 0);
    const int swz1 = swz_off(eidx, quad, 1);

    for (int i = tid; i < DE * HE; i += 256) we1s[i] = We1[i];
    if (tid < HE) be1s[tid] = be1[tid];
    dsl[tid] = dst_s[e0 + tid];

    const float4 ev0 = *(const float4*)(ed_s + (size_t)(e0 + tid) * 8);
    const float4 ev1 = *(const float4*)(ed_s + (size_t)(e0 + tid) * 8 + 4);
    float edr[8];
    edr[0] = ev0.x; edr[1] = ev0.y; edr[2] = ev0.z; edr[3] = ev0.w;
    edr[4] = ev1.x; edr[5] = ev1.y; edr[6] = ev1.z; edr[7] = ev1.w;

    short8x bhi[4];
#pragma unroll
    for (int et = 0; et < 4; ++et) {
        const int e = e0 + wv * 64 + et * 16 + eidx;
        const size_t hb = (size_t)src_s[e] * 32 + d0;
        bhi[et] = *(const short8x*)(hhi + hb);
    }

    short8x ring[4][2];
#define LDW(slot, kk)                                                  \
    do {                                                               \
        const unsigned short* _p = wth + ((size_t)(kk) << 10);         \
        ring[slot][0] = *(const short8x*)(_p + swz0);                  \
        ring[slot][1] = *(const short8x*)(_p + swz1);                  \
    } while (0)
    LDW(0, 0);
    LDW(1, 1);
    LDW(2, 2);

    f32x4 macc[4][2];
#pragma unroll
    for (int et = 0; et < 4; ++et) {
        macc[et][0] = (f32x4){0.f, 0.f, 0.f, 0.f};
        macc[et][1] = (f32x4){0.f, 0.f, 0.f, 0.f};
    }

    __syncthreads();

#pragma unroll 1
    for (int c = 0; c < 16; ++c) {
        float zreg[8];
#pragma unroll
        for (int m = 0; m < 8; ++m) {
            const int k = c * 8 + m;
            float acc = be1s[k];
#pragma unroll
            for (int j = 0; j < 8; ++j) acc += edr[j] * we1s[j * HE + k];
            zreg[m] = fmaxf(acc, 0.f);
        }
#pragma unroll
        for (int m = 0; m < 8; ++m) {
            const int k = c * 8 + m;
            const int slot = m & 3;
            const int pslot = (m + 3) & 3;
            int kn = k + 3;
            kn = (kn > 128) ? 128 : kn;
            LDW(pslot, kn);

            const short8x fh0 = ring[slot][0];
            const short8x fh1 = ring[slot][1];
#pragma unroll
            for (int et = 0; et < 4; ++et) {
                const float zk = __shfl(zreg[m], et * 16 + eidx);
                f32x4 t0 = {0.f, 0.f, 0.f, 0.f}, t1 = {0.f, 0.f, 0.f, 0.f};
                t0 = __builtin_amdgcn_mfma_f32_16x16x32_bf16(fh0, bhi[et], t0, 0, 0, 0);
                t1 = __builtin_amdgcn_mfma_f32_16x16x32_bf16(fh1, bhi[et], t1, 0, 0, 0);
                macc[et][0] += zk * t0;
                macc[et][1] += zk * t1;
            }
        }
    }

    {
        const short8x fh0 = ring[0][0];
        const short8x fh1 = ring[0][1];
#pragma unroll
        for (int et = 0; et < 4; ++et) {
            f32x4 t0 = {0.f, 0.f, 0.f, 0.f}, t1 = {0.f, 0.f, 0.f, 0.f};
            t0 = __builtin_amdgcn_mfma_f32_16x16x32_bf16(fh0, bhi[et], t0, 0, 0, 0);
            t1 = __builtin_amdgcn_mfma_f32_16x16x32_bf16(fh1, bhi[et], t1, 0, 0, 0);
            macc[et][0] += t0;
            macc[et][1] += t1;
        }
    }
#undef LDW

#pragma unroll
    for (int et = 0; et < 4; ++et) {
        const int eloc = wv * 64 + et * 16 + eidx;
        float* row = msgb + eloc * 17;
        row[quad * 4 + 0] = macc[et][0].x;
        row[quad * 4 + 1] = macc[et][0].y;
        row[quad * 4 + 2] = macc[et][0].z;
        row[quad * 4 + 3] = macc[et][0].w;
    }
    __syncthreads();
    {
        const int g = tid >> 4, fl = tid & 15;
        const int base = g * 16;
        float acc = 0.f;
        int cur = dsl[base];
        for (int i = 0; i < 16; ++i) {
            const int dnn = dsl[base + i];
            const float v = msgb[(base + i) * 17 + fl];
            if (dnn != cur) {
                atomicAdd(&agg[(size_t)cur * 32 + fl], acc);
                acc = 0.f;
                cur = dnn;
            }
            acc += v;
        }
        atomicAdd(&agg[(size_t)cur * 32 + fl], acc);
    }
    __syncthreads();

#pragma unroll
    for (int et = 0; et < 4; ++et) {
        const int eloc = wv * 64 + et * 16 + eidx;
        float* row = msgb + eloc * 17;
        row[quad * 4 + 0] = macc[et][1].x;
        row[quad * 4 + 1] = macc[et][1].y;
        row[quad * 4 + 2] = macc[et][1].z;
        row[quad * 4 + 3] = macc[et][1].w;
    }
    __syncthreads();
    {
        const int g = tid >> 4, fl = tid & 15;
        const int base = g * 16;
        float acc = 0.f;
        int cur = dsl[base];
        for (int i = 0; i < 16; ++i) {
            const int dnn = dsl[base + i];
            const float v = msgb[(base + i) * 17 + fl];
            if (dnn != cur) {
                atomicAdd(&agg[(size_t)cur * 32 + 16 + fl], acc);
                acc = 0.f;
                cur = dnn;
            }
            acc += v;
        }
        atomicAdd(&agg[(size_t)cur * 32 + 16 + fl], acc);
    }
}

// -------- MFMA msg v2 (fallback, base ws only): ring prefetch, z in regs, 3-pass
#define LDFRAG(slot, kk)                                          \
    do {                                                          \
        const unsigned short* _ph = wth + ((size_t)(kk) << 10);   \
        const unsigned short* _pl = wtl + ((size_t)(kk) << 10);   \
        ring[slot][0] = *(const short8x*)(_ph + b0);              \
        ring[slot][1] = *(const short8x*)(_ph + b1);              \
        ring[slot][2] = *(const short8x*)(_pl + b0);              \
        ring[slot][3] = *(const short8x*)(_pl + b1);              \
    } while (0)

__global__ __launch_bounds__(256) void k_msg_mfma(
    const float* __restrict__ ed, const float* __restrict__ We1,
    const float* __restrict__ be1,
    const unsigned short* __restrict__ wth, const unsigned short* __restrict__ wtl,
    const unsigned short* __restrict__ hhi, const unsigned short* __restrict__ hlo,
    const int* __restrict__ src, const int* __restrict__ dst,
    float* __restrict__ agg) {
    const int tid = threadIdx.x;
    const int e0 = blockIdx.x * 64;

    __shared__ float we1s[DE * HE];
    __shared__ float be1s[HE];

    for (int i = tid; i < DE * HE; i += 256) we1s[i] = We1[i];
    if (tid < HE) be1s[tid] = be1[tid];

    const int lane = tid & 63;
    const int wv = tid >> 6;
    const int eidx = lane & 15;
    const int quad = lane >> 4;
    const int eloc = wv * 16 + eidx;
    const int e = e0 + eloc;
    const int d0 = quad * 8;

    const int sn = src[e];
    const int dn = dst[e];

    const int b0 = swz_off(eidx, quad, 0);
    const int b1 = swz_off(eidx, quad, 1);

    const size_t hb = (size_t)sn * 32 + d0;
    const short8x bhi = *(const short8x*)(hhi + hb);
    const short8x blo = *(const short8x*)(hlo + hb);
    const float4 edv0 = *(const float4*)(ed + (size_t)e * 8);
    const float4 edv1 = *(const float4*)(ed + (size_t)e * 8 + 4);

    short8x ring[4][4];
    LDFRAG(0, 0);
    LDFRAG(1, 1);
    LDFRAG(2, 2);

    __syncthreads();

    float edr[8];
    edr[0] = edv0.x; edr[1] = edv0.y; edr[2] = edv0.z; edr[3] = edv0.w;
    edr[4] = edv1.x; edr[5] = edv1.y; edr[6] = edv1.z; edr[7] = edv1.w;
    float zreg[32];
#pragma unroll
    for (int m = 0; m < 32; ++m) {
        const int kk = (quad << 5) + m;
        float acc = be1s[kk];
#pragma unroll
        for (int j = 0; j < 8; ++j) acc += edr[j] * we1s[j * 128 + kk];
        zreg[m] = fmaxf(acc, 0.f);
    }

    f32x4 m0 = {0.f, 0.f, 0.f, 0.f}, m1 = {0.f, 0.f, 0.f, 0.f};

    for (int q = 0; q < 4; ++q) {
        const int bsrc = q * 16 + eidx;
#pragma unroll
        for (int m = 0; m < 32; ++m) {
            const int k = q * 32 + m;
            const int slot = m & 3;
            const int pslot = (m + 3) & 3;
            int kn = k + 3;
            kn = (kn > 128) ? 128 : kn;
            LDFRAG(pslot, kn);

            const float zk = __shfl(zreg[m], bsrc);

            f32x4 t0 = {0.f, 0.f, 0.f, 0.f}, t1 = {0.f, 0.f, 0.f, 0.f};
            t0 = __builtin_amdgcn_mfma_f32_16x16x32_bf16(ring[slot][0], bhi, t0, 0, 0, 0);
            t1 = __builtin_amdgcn_mfma_f32_16x16x32_bf16(ring[slot][1], bhi, t1, 0, 0, 0);
            t0 = __builtin_amdgcn_mfma_f32_16x16x32_bf16(ring[slot][2], bhi, t0, 0, 0, 0);
            t1 = __builtin_amdgcn_mfma_f32_16x16x32_bf16(ring[slot][3], bhi, t1, 0, 0, 0);
            t0 = __builtin_amdgcn_mfma_f32_16x16x32_bf16(ring[slot][0], blo, t0, 0, 0, 0);
            t1 = __builtin_amdgcn_mfma_f32_16x16x32_bf16(ring[slot][1], blo, t1, 0, 0, 0);

            m0 += zk * t0;
            m1 += zk * t1;
        }
    }
    {
        f32x4 t0 = {0.f, 0.f, 0.f, 0.f}, t1 = {0.f, 0.f, 0.f, 0.f};
        t0 = __builtin_amdgcn_mfma_f32_16x16x32_bf16(ring[0][0], bhi, t0, 0, 0, 0);
        t1 = __builtin_amdgcn_mfma_f32_16x16x32_bf16(ring[0][1], bhi, t1, 0, 0, 0);
        t0 = __builtin_amdgcn_mfma_f32_16x16x32_bf16(ring[0][2], bhi, t0, 0, 0, 0);
        t1 = __builtin_amdgcn_mfma_f32_16x16x32_bf16(ring[0][3], bhi, t1, 0, 0, 0);
        t0 = __builtin_amdgcn_mfma_f32_16x16x32_bf16(ring[0][0], blo, t0, 0, 0, 0);
        t1 = __builtin_amdgcn_mfma_f32_16x16x32_bf16(ring[0][1], blo, t1, 0, 0, 0);
        m0 += t0;
        m1 += t1;
    }

    float* ap = agg + (size_t)dn * 32 + quad * 4;
    atomicAdd(ap + 0, m0.x);
    atomicAdd(ap + 1, m0.y);
    atomicAdd(ap + 2, m0.z);
    atomicAdd(ap + 3, m0.w);
    atomicAdd(ap + 16 + 0, m1.x);
    atomicAdd(ap + 16 + 1, m1.y);
    atomicAdd(ap + 16 + 2, m1.z);
    atomicAdd(ap + 16 + 3, m1.w);
}

// -------- fallback (proven R2 path): recompute z per edge, fp32 VALU bilinear
__global__ __launch_bounds__(256) void k_msg_fused(
    const float* __restrict__ ed, const float* __restrict__ We1,
    const float* __restrict__ be1, const float* __restrict__ We2,
    const float* __restrict__ h, const int* __restrict__ src,
    const int* __restrict__ dst, float* __restrict__ agg) {
    const int tid = threadIdx.x;
    const int e0 = blockIdx.x * 64;
    __shared__ float we1s[DE * HE];
    __shared__ float be1s[HE];
    __shared__ float eds[64][9];
    __shared__ float zs[HE][64];
    __shared__ float hs[64][33];
    __shared__ float ws2s[4][1024];
    __shared__ int srcs[64];

    for (int i = tid; i < DE * HE; i += 256) we1s[i] = We1[i];
    if (tid < HE) be1s[tid] = be1[tid];
    if (tid < 64) srcs[tid] = src[e0 + tid];
    for (int i = tid; i < 64 * DE; i += 256) eds[i >> 3][i & 7] = ed[(size_t)e0 * DE + i];
    __syncthreads();

    {
        const int e = tid & 63, kb = tid >> 6;
        float edr[8];
#pragma unroll
        for (int j = 0; j < 8; ++j) edr[j] = eds[e][j];
        for (int m = 0; m < 32; ++m) {
            const int k = kb * 32 + m;
            float acc = be1s[k];
#pragma unroll
            for (int j = 0; j < 8; ++j) acc += edr[j] * we1s[j * HE + k];
            zs[k][e] = fmaxf(acc, 0.f);
        }
    }
    for (int i = tid; i < 64 * 32; i += 256) {
        const int e = i >> 5, d = i & 31;
        hs[e][d] = h[(size_t)srcs[e] * D + d];
    }
    __syncthreads();

    const int ep = tid & 31, fg = tid >> 5;
    float hr[2][32];
#pragma unroll
    for (int d = 0; d < 32; ++d) {
        hr[0][d] = hs[ep * 2][d];
        hr[1][d] = hs[ep * 2 + 1][d];
    }
    float acc[2][4];
#pragma unroll
    for (int i = 0; i < 2; ++i)
#pragma unroll
        for (int j = 0; j < 4; ++j) acc[i][j] = 0.f;

    for (int kc = 0; kc < 32; ++kc) {
        __syncthreads();
#pragma unroll
        for (int r = 0; r < 4; ++r) {
            const int idx4 = tid + 256 * r;
            const int kr = idx4 >> 8, c4 = idx4 & 255;
            *(float4*)&ws2s[kr][c4 * 4] =
                *(const float4*)(We2 + (size_t)(kc * 4 + kr) * 1024 + c4 * 4);
        }
        __syncthreads();
#pragma unroll
        for (int kk = 0; kk < 4; ++kk) {
            const int k = kc * 4 + kk;
            const float z0 = zs[k][ep * 2], z1 = zs[k][ep * 2 + 1];
#pragma unroll
            for (int d = 0; d < 32; ++d) {
                const float4 w4 = *(const float4*)&ws2s[kk][d * 32 + fg * 4];
                const float c0 = z0 * hr[0][d], c1 = z1 * hr[1][d];
                acc[0][0] += c0 * w4.x; acc[0][1] += c0 * w4.y;
                acc[0][2] += c0 * w4.z; acc[0][3] += c0 * w4.w;
                acc[1][0] += c1 * w4.x; acc[1][1] += c1 * w4.y;
                acc[1][2] += c1 * w4.z; acc[1][3] += c1 * w4.w;
            }
        }
    }
#pragma unroll
    for (int i = 0; i < 2; ++i) {
        const int e = e0 + ep * 2 + i;
        float* ap = &agg[(size_t)dst[e] * D + fg * 4];
#pragma unroll
        for (int j = 0; j < 4; ++j) atomicAdd(ap + j, acc[i][j]);
    }
}

// -------- GRU cell per node; reads agg then re-zeroes it (replaces memsets)
__global__ __launch_bounds__(256) void k_gru(
    const float* __restrict__ h, float* __restrict__ agg,
    const float* __restrict__ Wroot, const float* __restrict__ bconv,
    const float* __restrict__ Wih, const float* __restrict__ Whh,
    const float* __restrict__ bih, const float* __restrict__ bhh,
    float* __restrict__ hout,
    unsigned short* __restrict__ hhi, unsigned short* __restrict__ hlo) {
    const int idx = blockIdx.x * 256 + threadIdx.x;
    const int n = idx >> 5, f = idx & 31, nl = threadIdx.x >> 5;
    __shared__ float hsh[8][33], msh[8][33];
    const float hv = h[n * D + f];
    hsh[nl][f] = hv;
    __syncthreads();
    float m = bconv[f] + agg[n * D + f];
    agg[n * D + f] = 0.f;  // re-zero for next msg step
#pragma unroll
    for (int d = 0; d < 32; ++d) m += hsh[nl][d] * Wroot[d * D + f];
    m = fmaxf(m, 0.f);
    msh[nl][f] = m;
    __syncthreads();
    float gir = bih[f], giz = bih[D + f], gin = bih[2 * D + f];
    float ghr = bhh[f], ghz = bhh[D + f], ghn = bhh[2 * D + f];
#pragma unroll
    for (int d = 0; d < 32; ++d) {
        const float md = msh[nl][d], hd = hsh[nl][d];
        gir += md * Wih[f * D + d];
        giz += md * Wih[(D + f) * D + d];
        gin += md * Wih[(2 * D + f) * D + d];
        ghr += hd * Whh[f * D + d];
        ghz += hd * Whh[(D + f) * D + d];
        ghn += hd * Whh[(2 * D + f) * D + d];
    }
    const float r = sigf(gir + ghr);
    const float z = sigf(giz + ghz);
    const float nn2 = tanhf(gin + r * ghn);
    const float ho = (1.f - z) * nn2 + z * hv;
    hout[n * D + f] = ho;
    if (hhi) {
        unsigned short hi, lo;
        split_bf16(ho, hi, lo);
        hhi[idx] = hi;
        hlo[idx] = lo;
    }
}

// -------- all 12 Set2Set steps + output head in ONE kernel: block = graph
__global__ __launch_bounds__(256) void k_s2s_all(
    const float* __restrict__ h, const int* __restrict__ batch,
    const float* __restrict__ Wih, const float* __restrict__ Whh,
    const float* __restrict__ bih, const float* __restrict__ bhh,
    const float* __restrict__ Wout, const float* __restrict__ bout,
    float* __restrict__ ebuf, float* __restrict__ out) {
    const int b = blockIdx.x, t = threadIdx.x;
    __shared__ float qst[64], hls[32], cls[32], gates[128], qs[32];
    __shared__ float red[256];
    __shared__ float rsum[8][33];
    __shared__ int sse[2];
    if (t < 64) qst[t] = 0.f;
    if (t < 32) { hls[t] = 0.f; cls[t] = 0.f; }
    if (t < 2) {  // own graph segment via binary search on sorted batch
        const int target = b + t;
        int lo = 0, hi = NN;
        while (lo < hi) {
            int mid = (lo + hi) >> 1;
            if (batch[mid] < target) lo = mid + 1; else hi = mid;
        }
        sse[t] = lo;
    }
    __syncthreads();
    const int s0 = sse[0], s1 = sse[1];

    for (int s = 0; s < S2S; ++s) {
        if (t < 128) {
            float g = bih[t] + bhh[t];
#pragma unroll 8
            for (int j = 0; j < 64; ++j) g += qst[j] * Wih[t * 64 + j];
#pragma unroll 8
            for (int j = 0; j < 32; ++j) g += hls[j] * Whh[t * 32 + j];
            gates[t] = g;
        }
        __syncthreads();
        if (t < 32) {  // i,f,g,o order
            const float ig = sigf(gates[t]);
            const float fg = sigf(gates[32 + t]);
            const float gg = tanhf(gates[64 + t]);
            const float og = sigf(gates[96 + t]);
            const float c = fg * cls[t] + ig * gg;
            const float q = og * tanhf(c);
            cls[t] = c;
            hls[t] = q;
            qst[t] = q;
            qs[t] = q;
        }
        __syncthreads();
        float lmax = -3.4e38f;
        for (int n = s0 + t; n < s1; n += 256) {
            const float4* hv = (const float4*)(h + (size_t)n * D);
            float e = 0.f;
#pragma unroll
            for (int u = 0; u < 8; ++u) {
                const float4 v = hv[u];
                e += v.x * qs[u * 4] + v.y * qs[u * 4 + 1] + v.z * qs[u * 4 + 2] + v.w * qs[u * 4 + 3];
            }
            ebuf[n] = e;
            lmax = fmaxf(lmax, e);
        }
        red[t] = lmax;
        __syncthreads();
        for (int r2 = 128; r2 > 0; r2 >>= 1) {
            if (t < r2) red[t] = fmaxf(red[t], red[t + r2]);
            __syncthreads();
        }
        const float smax = red[0];
        __syncthreads();
        float lsum = 0.f;
        for (int n = s0 + t; n < s1; n += 256) {
            const float w = expf(ebuf[n] - smax);
            ebuf[n] = w;
            lsum += w;
        }
        red[t] = lsum;
        __syncthreads();
        for (int r2 = 128; r2 > 0; r2 >>= 1) {
            if (t < r2) red[t] += red[t + r2];
            __syncthreads();
        }
        const float den = red[0];
        const float inv = (den > 0.f) ? 1.f / den : 0.f;
        const int fl = t & 31, sl = t >> 5;
        float racc = 0.f;
        for (int n = s0 + sl; n < s1; n += 8) racc += ebuf[n] * h[(size_t)n * D + fl];
        rsum[sl][fl] = racc;
        __syncthreads();
        if (sl == 0) {
            float rv = 0.f;
#pragma unroll
            for (int u = 0; u < 8; ++u) rv += rsum[u][fl];
            qst[32 + fl] = rv * inv;
        }
        __syncthreads();  // qst[32..63] visible before next gates phase
    }

    if (t == 0) {  // fused output head
        float acc = bout[0];
#pragma unroll 8
        for (int j = 0; j < 64; ++j) acc += qst[j] * Wout[j];
        out[b] = acc;
    }
}

extern "C" void kernel_launch(void* const* d_in, const int* in_sizes, int n_in,
                              void* d_out, int out_size, void* d_ws, size_t ws_size,
                              hipStream_t stream) {
    const float* x     = (const float*)d_in[0];
    const float* ed    = (const float*)d_in[3];
    const int*   edges = (const int*)d_in[4];
    const int*   batch = (const int*)d_in[5];
    const float* Wi    = (const float*)d_in[6];
    const float* bi    = (const float*)d_in[7];
    const float* We1   = (const float*)d_in[8];
    const float* be1   = (const float*)d_in[9];
    const float* We2   = (const float*)d_in[10];
    const float* be2   = (const float*)d_in[11];
    const float* Wroot = (const float*)d_in[12];
    const float* bconv = (const float*)d_in[13];
    const float* gWih  = (const float*)d_in[14];
    const float* gWhh  = (const float*)d_in[15];
    const float* gbih  = (const float*)d_in[16];
    const float* gbhh  = (const float*)d_in[17];
    const float* lWih  = (const float*)d_in[18];
    const float* lWhh  = (const float*)d_in[19];
    const float* lbih  = (const float*)d_in[20];
    const float* lbhh  = (const float*)d_in[21];
    const float* Wout  = (const float*)d_in[22];
    const float* bout  = (const float*)d_in[23];
    float* out = (float*)d_out;

    const int* srcp = edges;
    const int* dstp = edges + NE;

    char* ws = (char*)d_ws;
    size_t off = 0;
    auto alloc = [&](size_t bytes) -> char* {
        char* p = ws + off;
        off += (bytes + 255) & ~(size_t)255;
        return p;
    };
    float* hA    = (float*)alloc((size_t)NN * D * 4);
    float* hB    = (float*)alloc((size_t)NN * D * 4);
    float* agg   = (float*)alloc((size_t)NN * D * 4);
    float* ebuf  = (float*)alloc((size_t)NN * 4);
    unsigned short* hhiA = (unsigned short*)alloc((size_t)NN * D * 2);
    unsigned short* hloA = (unsigned short*)alloc((size_t)NN * D * 2);
    unsigned short* hhiB = (unsigned short*)alloc((size_t)NN * D * 2);
    unsigned short* hloB = (unsigned short*)alloc((size_t)NN * D * 2);
    unsigned short* wth  = (unsigned short*)alloc((size_t)129 * 1024 * 2);
    unsigned short* wtl  = (unsigned short*)alloc((size_t)129 * 1024 * 2);
    const size_t base_off = off;
    const bool mfma_path = (ws_size >= base_off);
    // sorted-edge extras (~14 MB)
    int*   hist  = (int*)alloc((size_t)NN * 4);
    int*   offs  = (int*)alloc((size_t)NN * 4);
    int*   src_s = (int*)alloc((size_t)NE * 4);
    int*   dst_s = (int*)alloc((size_t)NE * 4);
    float* ed_s  = (float*)alloc((size_t)NE * 8 * 4);
    const bool mfma10_path = (ws_size >= off);

    // gate cascade: v17@6 if spill-free, else v17@5 if spill-free, else v12
    static int sel = -1;
    if (sel < 0) {
        hipFuncAttributes fa{};
        sel = 0;
        if (hipFuncGetAttributes(&fa, reinterpret_cast<const void*>(k_msg_mfma17_w6)) ==
                hipSuccess && fa.localSizeBytes == 0)
            sel = 6;
        else if (hipFuncGetAttributes(&fa, reinterpret_cast<const void*>(k_msg_mfma17_w5)) ==
                hipSuccess && fa.localSizeBytes == 0)
            sel = 5;
    }

    hipLaunchKernelGGL(k_input_linear, dim3(NN * D / 256), dim3(256), 0, stream, x, Wi, bi, hA,
                       mfma_path ? hhiA : (unsigned short*)nullptr,
                       mfma_path ? hloA : (unsigned short*)nullptr);
    if (mfma_path)
        hipLaunchKernelGGL(k_prep_w, dim3((129 * 1024 + 255) / 256), dim3(256), 0, stream,
                           We2, be2, wth, wtl);
    if (mfma10_path) {
        hipMemsetAsync(hist, 0, (size_t)NN * 4, stream);
        hipLaunchKernelGGL(k_hist, dim3(NE / 256), dim3(256), 0, stream, dstp, hist);
        hipLaunchKernelGGL(k_scan, dim3(1), dim3(256), 0, stream, hist, offs);
        hipLaunchKernelGGL(k_scatter, dim3(NE / 256), dim3(256), 0, stream,
                           srcp, dstp, ed, offs, src_s, dst_s, ed_s);
    }
    hipMemsetAsync(agg, 0, (size_t)NN * D * 4, stream);  // once; k_gru re-zeroes

    float* hcur = hA;
    float* hnxt = hB;
    unsigned short *hhic = hhiA, *hloc = hloA, *hhin = hhiB, *hlon = hloB;
    for (int t = 0; t < TST; ++t) {
        if (mfma10_path && sel == 6)
            hipLaunchKernelGGL(k_msg_mfma17_w6, dim3(NE / 128), dim3(256), 0, stream,
                               ed_s, We1, be1, wth, hhic, src_s, dst_s, agg);
        else if (mfma10_path && sel == 5)
            hipLaunchKernelGGL(k_msg_mfma17_w5, dim3(NE / 128), dim3(256), 0, stream,
                               ed_s, We1, be1, wth, hhic, src_s, dst_s, agg);
        else if (mfma10_path)
            hipLaunchKernelGGL(k_msg_mfma10, dim3(NE / 256), dim3(256), 0, stream,
                               ed_s, We1, be1, wth, hhic, src_s, dst_s, agg);
        else if (mfma_path)
            hipLaunchKernelGGL(k_msg_mfma, dim3(NE / 64), dim3(256), 0, stream,
                               ed, We1, be1, wth, wtl, hhic, hloc, srcp, dstp, agg);
        else
            hipLaunchKernelGGL(k_msg_fused, dim3(NE / 64), dim3(256), 0, stream,
                               ed, We1, be1, We2, hcur, srcp, dstp, agg);
        hipLaunchKernelGGL(k_gru, dim3(NN * D / 256), dim3(256), 0, stream,
                           hcur, agg, Wroot, bconv, gWih, gWhh, gbih, gbhh, hnxt,
                           mfma_path ? hhin : (unsigned short*)nullptr,
                           mfma_path ? hlon : (unsigned short*)nullptr);
        float* tf = hcur; hcur = hnxt; hnxt = tf;
        unsigned short* ts;
        ts = hhic; hhic = hhin; hhin = ts;
        ts = hloc; hloc = hlon; hlon = ts;
    }

    hipLaunchKernelGGL(k_s2s_all, dim3(NB), dim3(256), 0, stream,
                       hcur, batch, lWih, lWhh, lbih, lbhh, Wout, bout, ebuf, out);
    (void)in_sizes; (void)n_in; (void)out_size;
}

// Round 8
// 1666.894 us; speedup vs baseline: 1.0827x; 1.0365x over previous
//
#include <hip/hip_runtime.h>
#include <hip/hip_bf16.h>

#define NN 20000   // nodes
#define NE 320000  // edges
#define NB 64      // graphs
#define DIN 16
#define DE 8
#define HE 128
#define D 32
#define TST 8
#define S2S 12

typedef __attribute__((ext_vector_type(8))) short short8x;   // 8 bf16 = 4 VGPRs (MFMA A/B frag)
typedef __attribute__((ext_vector_type(4))) float f32x4;     // MFMA C/D frag

__device__ __forceinline__ float sigf(float x) { return 1.f / (1.f + expf(-x)); }

__device__ __forceinline__ void split_bf16(float x, unsigned short& hi, unsigned short& lo) {
    __hip_bfloat16 h = __float2bfloat16(x);
    hi = *(unsigned short*)&h;
    float r = x - __bfloat162float(h);
    __hip_bfloat16 l = __float2bfloat16(r);
    lo = *(unsigned short*)&l;
}

// XOR-swizzled element offset of an A-frag within a 1024-el k-row of Wt.
__device__ __forceinline__ int swz_off(int eidx, int quad, int tile) {
    const int u = eidx * 4 + quad;
    const int s = u ^ ((u >> 3) & 7);
    return tile * 512 + s * 8;
}

// -------- Wt[k][swz(f,d)] = We2[k][d*32+f] (k<128), row 128 = be2; hi/lo bf16
__global__ __launch_bounds__(256) void k_prep_w(
    const float* __restrict__ We2, const float* __restrict__ be2,
    unsigned short* __restrict__ wth, unsigned short* __restrict__ wtl) {
    int idx = blockIdx.x * 256 + threadIdx.x;
    if (idx >= 129 * 1024) return;
    int k = idx >> 10, rem = idx & 1023, f = rem >> 5, d = rem & 31;
    float v = (k < 128) ? We2[k * 1024 + d * 32 + f] : be2[d * 32 + f];
    unsigned short hi, lo;
    split_bf16(v, hi, lo);
    const int pos = k * 1024 + swz_off(f & 15, d >> 3, f >> 4) + (d & 7);
    wth[pos] = hi;
    wtl[pos] = lo;
}

// -------- counting sort of edges by dst
__global__ __launch_bounds__(256) void k_hist(const int* __restrict__ dst, int* __restrict__ hist) {
    const int e = blockIdx.x * 256 + threadIdx.x;
    atomicAdd(&hist[dst[e]], 1);
}

__global__ __launch_bounds__(256) void k_scan(const int* __restrict__ hist, int* __restrict__ offs) {
    __shared__ int part[256];
    const int tid = threadIdx.x;
    const int base = tid * 79;  // 256*79 = 20224 >= NN
    int s = 0;
    for (int i = 0; i < 79; ++i) {
        const int b = base + i;
        if (b < NN) s += hist[b];
    }
    part[tid] = s;
    __syncthreads();
    if (tid == 0) {
        int a = 0;
        for (int i = 0; i < 256; ++i) { const int v = part[i]; part[i] = a; a += v; }
    }
    __syncthreads();
    int a = part[tid];
    for (int i = 0; i < 79; ++i) {
        const int b = base + i;
        if (b < NN) { offs[b] = a; a += hist[b]; }
    }
}

__global__ __launch_bounds__(256) void k_scatter(
    const int* __restrict__ src, const int* __restrict__ dst, const float* __restrict__ ed,
    int* __restrict__ offs, int* __restrict__ src_s, int* __restrict__ dst_s,
    float* __restrict__ ed_s) {
    const int e = blockIdx.x * 256 + threadIdx.x;
    const int d = dst[e];
    const int pos = atomicAdd(&offs[d], 1);
    src_s[pos] = src[e];
    dst_s[pos] = d;
    const float4 a = *(const float4*)(ed + (size_t)e * 8);
    const float4 b = *(const float4*)(ed + (size_t)e * 8 + 4);
    *(float4*)(ed_s + (size_t)pos * 8) = a;
    *(float4*)(ed_s + (size_t)pos * 8 + 4) = b;
}

// -------- h0 = x @ W_in + b_in  (+ optional bf16 hi/lo split emit)
__global__ __launch_bounds__(256) void k_input_linear(
    const float* __restrict__ x, const float* __restrict__ Win,
    const float* __restrict__ bin, float* __restrict__ h,
    unsigned short* __restrict__ hhi, unsigned short* __restrict__ hlo) {
    int idx = blockIdx.x * 256 + threadIdx.x;
    int n = idx >> 5, f = idx & 31;
    float acc = bin[f];
#pragma unroll
    for (int d = 0; d < DIN; ++d) acc += x[n * DIN + d] * Win[d * D + f];
    h[idx] = acc;
    if (hhi) {
        unsigned short hi, lo;
        split_bf16(acc, hi, lo);
        hhi[idx] = hi;
        hlo[idx] = lo;
    }
}

// -------- MFMA msg v18: v12 dataflow (ET=4, ring-4, proven 131us) with
// instruction-count surgery. Occupancy chapter CLOSED by r7 evidence:
// 33%->131us (v12), 46%->133us (v17) -- not the limiter. v12 cycle
// accounting: VALU busy 56us (scale-fma 4/MFMA + z + LDW addressing),
// LDS pipe ~53us (z reads we1s as 64 ds_read_b32/chunk + 516 bpermutes).
// Edits: (1) z-compute j-outer with float4 LDS reads: 16 ds_read_b128
// instead of 64 ds_read_b32 per chunk (~2x fewer LDS cycles on z path);
// same j-ascending fp32 accumulation order per k -> bit-identical.
// (2) clamp-free prefetch: wth extended to 132 rows (129-131 loaded into
// dead ring slots, never consumed) so kn=k+3 is affine -> LLVM strength-
// reduces the address chain (the min() clamp blocked SR).
__global__ __launch_bounds__(256, 4) void k_msg_mfma18(
    const float* __restrict__ ed_s, const float* __restrict__ We1,
    const float* __restrict__ be1,
    const unsigned short* __restrict__ wth,
    const unsigned short* __restrict__ hhi,
    const int* __restrict__ src_s, const int* __restrict__ dst_s,
    float* __restrict__ agg) {
    const int tid = threadIdx.x;
    const int e0 = blockIdx.x * 256;

    __shared__ float msgb[256 * 17];  // 17408 B, epilogue only (2-pass over f)
    __shared__ float we1s[DE * HE];   // 4 KB
    __shared__ float be1s[HE];
    __shared__ int dsl[256];

    const int lane = tid & 63;
    const int wv = tid >> 6;
    const int eidx = lane & 15;
    const int quad = lane >> 4;
    const int d0 = quad * 8;
    const int swz0 = swz_off(eidx, quad, 0);
    const int swz1 = swz_off(eidx, quad, 1);

    for (int i = tid; i < DE * HE; i += 256) we1s[i] = We1[i];
    if (tid < HE) be1s[tid] = be1[tid];
    dsl[tid] = dst_s[e0 + tid];

    const float4 ev0 = *(const float4*)(ed_s + (size_t)(e0 + tid) * 8);
    const float4 ev1 = *(const float4*)(ed_s + (size_t)(e0 + tid) * 8 + 4);
    float edr[8];
    edr[0] = ev0.x; edr[1] = ev0.y; edr[2] = ev0.z; edr[3] = ev0.w;
    edr[4] = ev1.x; edr[5] = ev1.y; edr[6] = ev1.z; edr[7] = ev1.w;

    short8x bhi[4];
#pragma unroll
    for (int et = 0; et < 4; ++et) {
        const int e = e0 + wv * 64 + et * 16 + eidx;
        const size_t hb = (size_t)src_s[e] * 32 + d0;
        bhi[et] = *(const short8x*)(hhi + hb);
    }

    short8x ring[4][2];
#define LDW(slot, kk)                                                  \
    do {                                                               \
        const unsigned short* _p = wth + ((size_t)(kk) << 10);         \
        ring[slot][0] = *(const short8x*)(_p + swz0);                  \
        ring[slot][1] = *(const short8x*)(_p + swz1);                  \
    } while (0)
    LDW(0, 0);
    LDW(1, 1);
    LDW(2, 2);

    f32x4 macc[4][2];
#pragma unroll
    for (int et = 0; et < 4; ++et) {
        macc[et][0] = (f32x4){0.f, 0.f, 0.f, 0.f};
        macc[et][1] = (f32x4){0.f, 0.f, 0.f, 0.f};
    }

    __syncthreads();

#pragma unroll 1
    for (int c = 0; c < 16; ++c) {
        // z for this chunk's 8 k, this lane's edge. j-outer + float4 LDS
        // reads (16 b128 vs 64 b32); per-k order still j-ascending fp32.
        float zreg[8];
#pragma unroll
        for (int m = 0; m < 8; ++m) zreg[m] = be1s[c * 8 + m];
#pragma unroll
        for (int j = 0; j < 8; ++j) {
            const float4 wa = *(const float4*)&we1s[j * HE + c * 8];
            const float4 wb = *(const float4*)&we1s[j * HE + c * 8 + 4];
            const float ej = edr[j];
            zreg[0] += ej * wa.x; zreg[1] += ej * wa.y;
            zreg[2] += ej * wa.z; zreg[3] += ej * wa.w;
            zreg[4] += ej * wb.x; zreg[5] += ej * wb.y;
            zreg[6] += ej * wb.z; zreg[7] += ej * wb.w;
        }
#pragma unroll
        for (int m = 0; m < 8; ++m) zreg[m] = fmaxf(zreg[m], 0.f);

#pragma unroll
        for (int m = 0; m < 8; ++m) {
            const int k = c * 8 + m;
            const int slot = m & 3;
            const int pslot = (m + 3) & 3;
            const int kn = k + 3;  // affine: rows up to 130 exist (132 alloc'd)
            LDW(pslot, kn);

            const short8x fh0 = ring[slot][0];
            const short8x fh1 = ring[slot][1];
#pragma unroll
            for (int et = 0; et < 4; ++et) {
                const float zk = __shfl(zreg[m], et * 16 + eidx);
                f32x4 t0 = {0.f, 0.f, 0.f, 0.f}, t1 = {0.f, 0.f, 0.f, 0.f};
                t0 = __builtin_amdgcn_mfma_f32_16x16x32_bf16(fh0, bhi[et], t0, 0, 0, 0);
                t1 = __builtin_amdgcn_mfma_f32_16x16x32_bf16(fh1, bhi[et], t1, 0, 0, 0);
                macc[et][0] += zk * t0;
                macc[et][1] += zk * t1;
            }
        }
    }

    {   // k = 128: be2 virtual row, z == 1; slot 0 holds row 128 (kn@k=125)
        const short8x fh0 = ring[0][0];
        const short8x fh1 = ring[0][1];
#pragma unroll
        for (int et = 0; et < 4; ++et) {
            f32x4 t0 = {0.f, 0.f, 0.f, 0.f}, t1 = {0.f, 0.f, 0.f, 0.f};
            t0 = __builtin_amdgcn_mfma_f32_16x16x32_bf16(fh0, bhi[et], t0, 0, 0, 0);
            t1 = __builtin_amdgcn_mfma_f32_16x16x32_bf16(fh1, bhi[et], t1, 0, 0, 0);
            macc[et][0] += t0;
            macc[et][1] += t1;
        }
    }
#undef LDW

    // ---- epilogue pass 0: f 0..15 (macc[et][0]) ----
#pragma unroll
    for (int et = 0; et < 4; ++et) {
        const int eloc = wv * 64 + et * 16 + eidx;
        float* row = msgb + eloc * 17;
        row[quad * 4 + 0] = macc[et][0].x;
        row[quad * 4 + 1] = macc[et][0].y;
        row[quad * 4 + 2] = macc[et][0].z;
        row[quad * 4 + 3] = macc[et][0].w;
    }
    __syncthreads();
    {
        const int g = tid >> 4, fl = tid & 15;
        const int base = g * 16;
        float acc = 0.f;
        int cur = dsl[base];
        for (int i = 0; i < 16; ++i) {
            const int dnn = dsl[base + i];
            const float v = msgb[(base + i) * 17 + fl];
            if (dnn != cur) {
                atomicAdd(&agg[(size_t)cur * 32 + fl], acc);
                acc = 0.f;
                cur = dnn;
            }
            acc += v;
        }
        atomicAdd(&agg[(size_t)cur * 32 + fl], acc);
    }
    __syncthreads();

    // ---- epilogue pass 1: f 16..31 (macc[et][1]) ----
#pragma unroll
    for (int et = 0; et < 4; ++et) {
        const int eloc = wv * 64 + et * 16 + eidx;
        float* row = msgb + eloc * 17;
        row[quad * 4 + 0] = macc[et][1].x;
        row[quad * 4 + 1] = macc[et][1].y;
        row[quad * 4 + 2] = macc[et][1].z;
        row[quad * 4 + 3] = macc[et][1].w;
    }
    __syncthreads();
    {
        const int g = tid >> 4, fl = tid & 15;
        const int base = g * 16;
        float acc = 0.f;
        int cur = dsl[base];
        for (int i = 0; i < 16; ++i) {
            const int dnn = dsl[base + i];
            const float v = msgb[(base + i) * 17 + fl];
            if (dnn != cur) {
                atomicAdd(&agg[(size_t)cur * 32 + 16 + fl], acc);
                acc = 0.f;
                cur = dnn;
            }
            acc += v;
        }
        atomicAdd(&agg[(size_t)cur * 32 + 16 + fl], acc);
    }
}

// -------- MFMA msg v2 (fallback, base ws only): ring prefetch, z in regs, 3-pass
#define LDFRAG(slot, kk)                                          \
    do {                                                          \
        const unsigned short* _ph = wth + ((size_t)(kk) << 10);   \
        const unsigned short* _pl = wtl + ((size_t)(kk) << 10);   \
        ring[slot][0] = *(const short8x*)(_ph + b0);              \
        ring[slot][1] = *(const short8x*)(_ph + b1);              \
        ring[slot][2] = *(const short8x*)(_pl + b0);              \
        ring[slot][3] = *(const short8x*)(_pl + b1);              \
    } while (0)

__global__ __launch_bounds__(256) void k_msg_mfma(
    const float* __restrict__ ed, const float* __restrict__ We1,
    const float* __restrict__ be1,
    const unsigned short* __restrict__ wth, const unsigned short* __restrict__ wtl,
    const unsigned short* __restrict__ hhi, const unsigned short* __restrict__ hlo,
    const int* __restrict__ src, const int* __restrict__ dst,
    float* __restrict__ agg) {
    const int tid = threadIdx.x;
    const int e0 = blockIdx.x * 64;

    __shared__ float we1s[DE * HE];
    __shared__ float be1s[HE];

    for (int i = tid; i < DE * HE; i += 256) we1s[i] = We1[i];
    if (tid < HE) be1s[tid] = be1[tid];

    const int lane = tid & 63;
    const int wv = tid >> 6;
    const int eidx = lane & 15;
    const int quad = lane >> 4;
    const int eloc = wv * 16 + eidx;
    const int e = e0 + eloc;
    const int d0 = quad * 8;

    const int sn = src[e];
    const int dn = dst[e];

    const int b0 = swz_off(eidx, quad, 0);
    const int b1 = swz_off(eidx, quad, 1);

    const size_t hb = (size_t)sn * 32 + d0;
    const short8x bhi = *(const short8x*)(hhi + hb);
    const short8x blo = *(const short8x*)(hlo + hb);
    const float4 edv0 = *(const float4*)(ed + (size_t)e * 8);
    const float4 edv1 = *(const float4*)(ed + (size_t)e * 8 + 4);

    short8x ring[4][4];
    LDFRAG(0, 0);
    LDFRAG(1, 1);
    LDFRAG(2, 2);

    __syncthreads();

    float edr[8];
    edr[0] = edv0.x; edr[1] = edv0.y; edr[2] = edv0.z; edr[3] = edv0.w;
    edr[4] = edv1.x; edr[5] = edv1.y; edr[6] = edv1.z; edr[7] = edv1.w;
    float zreg[32];
#pragma unroll
    for (int m = 0; m < 32; ++m) {
        const int kk = (quad << 5) + m;
        float acc = be1s[kk];
#pragma unroll
        for (int j = 0; j < 8; ++j) acc += edr[j] * we1s[j * 128 + kk];
        zreg[m] = fmaxf(acc, 0.f);
    }

    f32x4 m0 = {0.f, 0.f, 0.f, 0.f}, m1 = {0.f, 0.f, 0.f, 0.f};

    for (int q = 0; q < 4; ++q) {
        const int bsrc = q * 16 + eidx;
#pragma unroll
        for (int m = 0; m < 32; ++m) {
            const int k = q * 32 + m;
            const int slot = m & 3;
            const int pslot = (m + 3) & 3;
            int kn = k + 3;
            kn = (kn > 128) ? 128 : kn;
            LDFRAG(pslot, kn);

            const float zk = __shfl(zreg[m], bsrc);

            f32x4 t0 = {0.f, 0.f, 0.f, 0.f}, t1 = {0.f, 0.f, 0.f, 0.f};
            t0 = __builtin_amdgcn_mfma_f32_16x16x32_bf16(ring[slot][0], bhi, t0, 0, 0, 0);
            t1 = __builtin_amdgcn_mfma_f32_16x16x32_bf16(ring[slot][1], bhi, t1, 0, 0, 0);
            t0 = __builtin_amdgcn_mfma_f32_16x16x32_bf16(ring[slot][2], bhi, t0, 0, 0, 0);
            t1 = __builtin_amdgcn_mfma_f32_16x16x32_bf16(ring[slot][3], bhi, t1, 0, 0, 0);
            t0 = __builtin_amdgcn_mfma_f32_16x16x32_bf16(ring[slot][0], blo, t0, 0, 0, 0);
            t1 = __builtin_amdgcn_mfma_f32_16x16x32_bf16(ring[slot][1], blo, t1, 0, 0, 0);

            m0 += zk * t0;
            m1 += zk * t1;
        }
    }
    {
        f32x4 t0 = {0.f, 0.f, 0.f, 0.f}, t1 = {0.f, 0.f, 0.f, 0.f};
        t0 = __builtin_amdgcn_mfma_f32_16x16x32_bf16(ring[0][0], bhi, t0, 0, 0, 0);
        t1 = __builtin_amdgcn_mfma_f32_16x16x32_bf16(ring[0][1], bhi, t1, 0, 0, 0);
        t0 = __builtin_amdgcn_mfma_f32_16x16x32_bf16(ring[0][2], bhi, t0, 0, 0, 0);
        t1 = __builtin_amdgcn_mfma_f32_16x16x32_bf16(ring[0][3], bhi, t1, 0, 0, 0);
        t0 = __builtin_amdgcn_mfma_f32_16x16x32_bf16(ring[0][0], blo, t0, 0, 0, 0);
        t1 = __builtin_amdgcn_mfma_f32_16x16x32_bf16(ring[0][1], blo, t1, 0, 0, 0);
        m0 += t0;
        m1 += t1;
    }

    float* ap = agg + (size_t)dn * 32 + quad * 4;
    atomicAdd(ap + 0, m0.x);
    atomicAdd(ap + 1, m0.y);
    atomicAdd(ap + 2, m0.z);
    atomicAdd(ap + 3, m0.w);
    atomicAdd(ap + 16 + 0, m1.x);
    atomicAdd(ap + 16 + 1, m1.y);
    atomicAdd(ap + 16 + 2, m1.z);
    atomicAdd(ap + 16 + 3, m1.w);
}

// -------- fallback (proven R2 path): recompute z per edge, fp32 VALU bilinear
__global__ __launch_bounds__(256) void k_msg_fused(
    const float* __restrict__ ed, const float* __restrict__ We1,
    const float* __restrict__ be1, const float* __restrict__ We2,
    const float* __restrict__ h, const int* __restrict__ src,
    const int* __restrict__ dst, float* __restrict__ agg) {
    const int tid = threadIdx.x;
    const int e0 = blockIdx.x * 64;
    __shared__ float we1s[DE * HE];
    __shared__ float be1s[HE];
    __shared__ float eds[64][9];
    __shared__ float zs[HE][64];
    __shared__ float hs[64][33];
    __shared__ float ws2s[4][1024];
    __shared__ int srcs[64];

    for (int i = tid; i < DE * HE; i += 256) we1s[i] = We1[i];
    if (tid < HE) be1s[tid] = be1[tid];
    if (tid < 64) srcs[tid] = src[e0 + tid];
    for (int i = tid; i < 64 * DE; i += 256) eds[i >> 3][i & 7] = ed[(size_t)e0 * DE + i];
    __syncthreads();

    {
        const int e = tid & 63, kb = tid >> 6;
        float edr[8];
#pragma unroll
        for (int j = 0; j < 8; ++j) edr[j] = eds[e][j];
        for (int m = 0; m < 32; ++m) {
            const int k = kb * 32 + m;
            float acc = be1s[k];
#pragma unroll
            for (int j = 0; j < 8; ++j) acc += edr[j] * we1s[j * HE + k];
            zs[k][e] = fmaxf(acc, 0.f);
        }
    }
    for (int i = tid; i < 64 * 32; i += 256) {
        const int e = i >> 5, d = i & 31;
        hs[e][d] = h[(size_t)srcs[e] * D + d];
    }
    __syncthreads();

    const int ep = tid & 31, fg = tid >> 5;
    float hr[2][32];
#pragma unroll
    for (int d = 0; d < 32; ++d) {
        hr[0][d] = hs[ep * 2][d];
        hr[1][d] = hs[ep * 2 + 1][d];
    }
    float acc[2][4];
#pragma unroll
    for (int i = 0; i < 2; ++i)
#pragma unroll
        for (int j = 0; j < 4; ++j) acc[i][j] = 0.f;

    for (int kc = 0; kc < 32; ++kc) {
        __syncthreads();
#pragma unroll
        for (int r = 0; r < 4; ++r) {
            const int idx4 = tid + 256 * r;
            const int kr = idx4 >> 8, c4 = idx4 & 255;
            *(float4*)&ws2s[kr][c4 * 4] =
                *(const float4*)(We2 + (size_t)(kc * 4 + kr) * 1024 + c4 * 4);
        }
        __syncthreads();
#pragma unroll
        for (int kk = 0; kk < 4; ++kk) {
            const int k = kc * 4 + kk;
            const float z0 = zs[k][ep * 2], z1 = zs[k][ep * 2 + 1];
#pragma unroll
            for (int d = 0; d < 32; ++d) {
                const float4 w4 = *(const float4*)&ws2s[kk][d * 32 + fg * 4];
                const float c0 = z0 * hr[0][d], c1 = z1 * hr[1][d];
                acc[0][0] += c0 * w4.x; acc[0][1] += c0 * w4.y;
                acc[0][2] += c0 * w4.z; acc[0][3] += c0 * w4.w;
                acc[1][0] += c1 * w4.x; acc[1][1] += c1 * w4.y;
                acc[1][2] += c1 * w4.z; acc[1][3] += c1 * w4.w;
            }
        }
    }
#pragma unroll
    for (int i = 0; i < 2; ++i) {
        const int e = e0 + ep * 2 + i;
        float* ap = &agg[(size_t)dst[e] * D + fg * 4];
#pragma unroll
        for (int j = 0; j < 4; ++j) atomicAdd(ap + j, acc[i][j]);
    }
}

// -------- GRU cell per node; reads agg then re-zeroes it (replaces memsets)
__global__ __launch_bounds__(256) void k_gru(
    const float* __restrict__ h, float* __restrict__ agg,
    const float* __restrict__ Wroot, const float* __restrict__ bconv,
    const float* __restrict__ Wih, const float* __restrict__ Whh,
    const float* __restrict__ bih, const float* __restrict__ bhh,
    float* __restrict__ hout,
    unsigned short* __restrict__ hhi, unsigned short* __restrict__ hlo) {
    const int idx = blockIdx.x * 256 + threadIdx.x;
    const int n = idx >> 5, f = idx & 31, nl = threadIdx.x >> 5;
    __shared__ float hsh[8][33], msh[8][33];
    const float hv = h[n * D + f];
    hsh[nl][f] = hv;
    __syncthreads();
    float m = bconv[f] + agg[n * D + f];
    agg[n * D + f] = 0.f;  // re-zero for next msg step
#pragma unroll
    for (int d = 0; d < 32; ++d) m += hsh[nl][d] * Wroot[d * D + f];
    m = fmaxf(m, 0.f);
    msh[nl][f] = m;
    __syncthreads();
    float gir = bih[f], giz = bih[D + f], gin = bih[2 * D + f];
    float ghr = bhh[f], ghz = bhh[D + f], ghn = bhh[2 * D + f];
#pragma unroll
    for (int d = 0; d < 32; ++d) {
        const float md = msh[nl][d], hd = hsh[nl][d];
        gir += md * Wih[f * D + d];
        giz += md * Wih[(D + f) * D + d];
        gin += md * Wih[(2 * D + f) * D + d];
        ghr += hd * Whh[f * D + d];
        ghz += hd * Whh[(D + f) * D + d];
        ghn += hd * Whh[(2 * D + f) * D + d];
    }
    const float r = sigf(gir + ghr);
    const float z = sigf(giz + ghz);
    const float nn2 = tanhf(gin + r * ghn);
    const float ho = (1.f - z) * nn2 + z * hv;
    hout[n * D + f] = ho;
    if (hhi) {
        unsigned short hi, lo;
        split_bf16(ho, hi, lo);
        hhi[idx] = hi;
        hlo[idx] = lo;
    }
}

// -------- all 12 Set2Set steps + output head in ONE kernel: block = graph
// v18: attention weights cached in LDS (wls) instead of global ebuf
// round-trips (3 global passes x 12 steps removed); guarded fallback to
// ebuf if a graph segment exceeds the LDS cache (expected max ~380 << 640).
__global__ __launch_bounds__(256) void k_s2s_all(
    const float* __restrict__ h, const int* __restrict__ batch,
    const float* __restrict__ Wih, const float* __restrict__ Whh,
    const float* __restrict__ bih, const float* __restrict__ bhh,
    const float* __restrict__ Wout, const float* __restrict__ bout,
    float* __restrict__ ebuf, float* __restrict__ out) {
    const int b = blockIdx.x, t = threadIdx.x;
    __shared__ float qst[64], hls[32], cls[32], gates[128], qs[32];
    __shared__ float red[256];
    __shared__ float rsum[8][33];
    __shared__ float wls[640];
    __shared__ int sse[2];
    if (t < 64) qst[t] = 0.f;
    if (t < 32) { hls[t] = 0.f; cls[t] = 0.f; }
    if (t < 2) {  // own graph segment via binary search on sorted batch
        const int target = b + t;
        int lo = 0, hi = NN;
        while (lo < hi) {
            int mid = (lo + hi) >> 1;
            if (batch[mid] < target) lo = mid + 1; else hi = mid;
        }
        sse[t] = lo;
    }
    __syncthreads();
    const int s0 = sse[0], s1 = sse[1];
    const bool fit = (s1 - s0) <= 640;

    for (int s = 0; s < S2S; ++s) {
        if (t < 128) {
            float g = bih[t] + bhh[t];
#pragma unroll 8
            for (int j = 0; j < 64; ++j) g += qst[j] * Wih[t * 64 + j];
#pragma unroll 8
            for (int j = 0; j < 32; ++j) g += hls[j] * Whh[t * 32 + j];
            gates[t] = g;
        }
        __syncthreads();
        if (t < 32) {  // i,f,g,o order
            const float ig = sigf(gates[t]);
            const float fg = sigf(gates[32 + t]);
            const float gg = tanhf(gates[64 + t]);
            const float og = sigf(gates[96 + t]);
            const float c = fg * cls[t] + ig * gg;
            const float q = og * tanhf(c);
            cls[t] = c;
            hls[t] = q;
            qst[t] = q;
            qs[t] = q;
        }
        __syncthreads();
        float lmax = -3.4e38f;
        for (int n = s0 + t; n < s1; n += 256) {
            const float4* hv = (const float4*)(h + (size_t)n * D);
            float e = 0.f;
#pragma unroll
            for (int u = 0; u < 8; ++u) {
                const float4 v = hv[u];
                e += v.x * qs[u * 4] + v.y * qs[u * 4 + 1] + v.z * qs[u * 4 + 2] + v.w * qs[u * 4 + 3];
            }
            if (fit) wls[n - s0] = e; else ebuf[n] = e;
            lmax = fmaxf(lmax, e);
        }
        red[t] = lmax;
        __syncthreads();
        for (int r2 = 128; r2 > 0; r2 >>= 1) {
            if (t < r2) red[t] = fmaxf(red[t], red[t + r2]);
            __syncthreads();
        }
        const float smax = red[0];
        __syncthreads();
        float lsum = 0.f;
        for (int n = s0 + t; n < s1; n += 256) {
            const float ev = fit ? wls[n - s0] : ebuf[n];
            const float w = expf(ev - smax);
            if (fit) wls[n - s0] = w; else ebuf[n] = w;
            lsum += w;
        }
        red[t] = lsum;
        __syncthreads();
        for (int r2 = 128; r2 > 0; r2 >>= 1) {
            if (t < r2) red[t] += red[t + r2];
            __syncthreads();
        }
        const float den = red[0];
        const float inv = (den > 0.f) ? 1.f / den : 0.f;
        const int fl = t & 31, sl = t >> 5;
        float racc = 0.f;
        for (int n = s0 + sl; n < s1; n += 8)
            racc += (fit ? wls[n - s0] : ebuf[n]) * h[(size_t)n * D + fl];
        rsum[sl][fl] = racc;
        __syncthreads();
        if (sl == 0) {
            float rv = 0.f;
#pragma unroll
            for (int u = 0; u < 8; ++u) rv += rsum[u][fl];
            qst[32 + fl] = rv * inv;
        }
        __syncthreads();  // qst[32..63] + wls reads done before next step
    }

    if (t == 0) {  // fused output head
        float acc = bout[0];
#pragma unroll 8
        for (int j = 0; j < 64; ++j) acc += qst[j] * Wout[j];
        out[b] = acc;
    }
}

extern "C" void kernel_launch(void* const* d_in, const int* in_sizes, int n_in,
                              void* d_out, int out_size, void* d_ws, size_t ws_size,
                              hipStream_t stream) {
    const float* x     = (const float*)d_in[0];
    const float* ed    = (const float*)d_in[3];
    const int*   edges = (const int*)d_in[4];
    const int*   batch = (const int*)d_in[5];
    const float* Wi    = (const float*)d_in[6];
    const float* bi    = (const float*)d_in[7];
    const float* We1   = (const float*)d_in[8];
    const float* be1   = (const float*)d_in[9];
    const float* We2   = (const float*)d_in[10];
    const float* be2   = (const float*)d_in[11];
    const float* Wroot = (const float*)d_in[12];
    const float* bconv = (const float*)d_in[13];
    const float* gWih  = (const float*)d_in[14];
    const float* gWhh  = (const float*)d_in[15];
    const float* gbih  = (const float*)d_in[16];
    const float* gbhh  = (const float*)d_in[17];
    const float* lWih  = (const float*)d_in[18];
    const float* lWhh  = (const float*)d_in[19];
    const float* lbih  = (const float*)d_in[20];
    const float* lbhh  = (const float*)d_in[21];
    const float* Wout  = (const float*)d_in[22];
    const float* bout  = (const float*)d_in[23];
    float* out = (float*)d_out;

    const int* srcp = edges;
    const int* dstp = edges + NE;

    char* ws = (char*)d_ws;
    size_t off = 0;
    auto alloc = [&](size_t bytes) -> char* {
        char* p = ws + off;
        off += (bytes + 255) & ~(size_t)255;
        return p;
    };
    float* hA    = (float*)alloc((size_t)NN * D * 4);
    float* hB    = (float*)alloc((size_t)NN * D * 4);
    float* agg   = (float*)alloc((size_t)NN * D * 4);
    float* ebuf  = (float*)alloc((size_t)NN * 4);
    unsigned short* hhiA = (unsigned short*)alloc((size_t)NN * D * 2);
    unsigned short* hloA = (unsigned short*)alloc((size_t)NN * D * 2);
    unsigned short* hhiB = (unsigned short*)alloc((size_t)NN * D * 2);
    unsigned short* hloB = (unsigned short*)alloc((size_t)NN * D * 2);
    // wth: 132 rows (129 real + 3 overrun rows read into dead ring slots)
    unsigned short* wth  = (unsigned short*)alloc((size_t)132 * 1024 * 2);
    unsigned short* wtl  = (unsigned short*)alloc((size_t)129 * 1024 * 2);
    const size_t base_off = off;
    const bool mfma_path = (ws_size >= base_off);
    // sorted-edge extras (~14 MB)
    int*   hist  = (int*)alloc((size_t)NN * 4);
    int*   offs  = (int*)alloc((size_t)NN * 4);
    int*   src_s = (int*)alloc((size_t)NE * 4);
    int*   dst_s = (int*)alloc((size_t)NE * 4);
    float* ed_s  = (float*)alloc((size_t)NE * 8 * 4);
    const bool mfma10_path = (ws_size >= off);

    hipLaunchKernelGGL(k_input_linear, dim3(NN * D / 256), dim3(256), 0, stream, x, Wi, bi, hA,
                       mfma_path ? hhiA : (unsigned short*)nullptr,
                       mfma_path ? hloA : (unsigned short*)nullptr);
    if (mfma_path)
        hipLaunchKernelGGL(k_prep_w, dim3((129 * 1024 + 255) / 256), dim3(256), 0, stream,
                           We2, be2, wth, wtl);
    if (mfma10_path) {
        hipMemsetAsync(hist, 0, (size_t)NN * 4, stream);
        hipLaunchKernelGGL(k_hist, dim3(NE / 256), dim3(256), 0, stream, dstp, hist);
        hipLaunchKernelGGL(k_scan, dim3(1), dim3(256), 0, stream, hist, offs);
        hipLaunchKernelGGL(k_scatter, dim3(NE / 256), dim3(256), 0, stream,
                           srcp, dstp, ed, offs, src_s, dst_s, ed_s);
    }
    hipMemsetAsync(agg, 0, (size_t)NN * D * 4, stream);  // once; k_gru re-zeroes

    float* hcur = hA;
    float* hnxt = hB;
    unsigned short *hhic = hhiA, *hloc = hloA, *hhin = hhiB, *hlon = hloB;
    for (int t = 0; t < TST; ++t) {
        if (mfma10_path)
            hipLaunchKernelGGL(k_msg_mfma18, dim3(NE / 256), dim3(256), 0, stream,
                               ed_s, We1, be1, wth, hhic, src_s, dst_s, agg);
        else if (mfma_path)
            hipLaunchKernelGGL(k_msg_mfma, dim3(NE / 64), dim3(256), 0, stream,
                               ed, We1, be1, wth, wtl, hhic, hloc, srcp, dstp, agg);
        else
            hipLaunchKernelGGL(k_msg_fused, dim3(NE / 64), dim3(256), 0, stream,
                               ed, We1, be1, We2, hcur, srcp, dstp, agg);
        hipLaunchKernelGGL(k_gru, dim3(NN * D / 256), dim3(256), 0, stream,
                           hcur, agg, Wroot, bconv, gWih, gWhh, gbih, gbhh, hnxt,
                           mfma_path ? hhin : (unsigned short*)nullptr,
                           mfma_path ? hlon : (unsigned short*)nullptr);
        float* tf = hcur; hcur = hnxt; hnxt = tf;
        unsigned short* ts;
        ts = hhic; hhic = hhin; hhin = ts;
        ts = hloc; hloc = hlon; hlon = ts;
    }

    hipLaunchKernelGGL(k_s2s_all, dim3(NB), dim3(256), 0, stream,
                       hcur, batch, lWih, lWhh, lbih, lbhh, Wout, bout, ebuf, out);
    (void)in_sizes; (void)n_in; (void)out_size;
}

// Round 9
// 1284.002 us; speedup vs baseline: 1.4055x; 1.2982x over previous
//
#include <hip/hip_runtime.h>
#include <hip/hip_bf16.h>

#define NN 20000   // nodes
#define NE 320000  // edges
#define NB 64      // graphs
#define DIN 16
#define DE 8
#define HE 128
#define D 32
#define TST 8
#define S2S 12

typedef __attribute__((ext_vector_type(8))) short short8x;   // 8 bf16 = 4 VGPRs (MFMA A/B frag)
typedef __attribute__((ext_vector_type(4))) float f32x4;     // MFMA C/D frag

__device__ __forceinline__ float sigf(float x) { return 1.f / (1.f + expf(-x)); }

__device__ __forceinline__ void split_bf16(float x, unsigned short& hi, unsigned short& lo) {
    __hip_bfloat16 h = __float2bfloat16(x);
    hi = *(unsigned short*)&h;
    float r = x - __bfloat162float(h);
    __hip_bfloat16 l = __float2bfloat16(r);
    lo = *(unsigned short*)&l;
}

// XOR-swizzled element offset of an A-frag within a 1024-el k-row of Wt.
__device__ __forceinline__ int swz_off(int eidx, int quad, int tile) {
    const int u = eidx * 4 + quad;
    const int s = u ^ ((u >> 3) & 7);
    return tile * 512 + s * 8;
}

// -------- Wt[k][swz(f,d)] = We2[k][d*32+f] (k<128), row 128 = be2; hi/lo bf16
__global__ __launch_bounds__(256) void k_prep_w(
    const float* __restrict__ We2, const float* __restrict__ be2,
    unsigned short* __restrict__ wth, unsigned short* __restrict__ wtl) {
    int idx = blockIdx.x * 256 + threadIdx.x;
    if (idx >= 129 * 1024) return;
    int k = idx >> 10, rem = idx & 1023, f = rem >> 5, d = rem & 31;
    float v = (k < 128) ? We2[k * 1024 + d * 32 + f] : be2[d * 32 + f];
    unsigned short hi, lo;
    split_bf16(v, hi, lo);
    const int pos = k * 1024 + swz_off(f & 15, d >> 3, f >> 4) + (d & 7);
    wth[pos] = hi;
    wtl[pos] = lo;
}

// -------- transpose small weight matrices for lane-coalesced reads.
// Evidence (r8): k_gru ~60us and s2s gates-phase dominated by row-indexed-
// by-lane global loads (Wih[f*D+d], f=lane -> 32-64 distinct cache lines
// PER LOAD INSTRUCTION). Transposed layout makes lanes read consecutive
// floats (1-2 lines/instr, L1-resident 28KB). Same values, same
// accumulation order -> gru bit-identical.
__global__ __launch_bounds__(256) void k_prep_t(
    const float* __restrict__ gWih, const float* __restrict__ gWhh,
    const float* __restrict__ lWih, const float* __restrict__ lWhh,
    float* __restrict__ gWihT, float* __restrict__ gWhhT,
    float* __restrict__ lWihT, float* __restrict__ lWhhT) {
    const int idx = blockIdx.x * 256 + threadIdx.x;
    if (idx < 3072) {                      // gWih [96][32] -> [32][96]
        const int r = idx >> 5, d = idx & 31;
        gWihT[d * 96 + r] = gWih[idx];
    } else if (idx < 6144) {               // gWhh [96][32] -> [32][96]
        const int i = idx - 3072;
        const int r = i >> 5, d = i & 31;
        gWhhT[d * 96 + r] = gWhh[i];
    } else if (idx < 6144 + 8192) {        // lWih [128][64] -> [64][128]
        const int i = idx - 6144;
        const int r = i >> 6, j = i & 63;
        lWihT[j * 128 + r] = lWih[i];
    } else if (idx < 6144 + 8192 + 4096) { // lWhh [128][32] -> [32][128]
        const int i = idx - 14336;
        const int r = i >> 5, j = i & 31;
        lWhhT[j * 128 + r] = lWhh[i];
    }
}

// -------- counting sort of edges by dst
__global__ __launch_bounds__(256) void k_hist(const int* __restrict__ dst, int* __restrict__ hist) {
    const int e = blockIdx.x * 256 + threadIdx.x;
    atomicAdd(&hist[dst[e]], 1);
}

__global__ __launch_bounds__(256) void k_scan(const int* __restrict__ hist, int* __restrict__ offs) {
    __shared__ int part[256];
    const int tid = threadIdx.x;
    const int base = tid * 79;  // 256*79 = 20224 >= NN
    int s = 0;
    for (int i = 0; i < 79; ++i) {
        const int b = base + i;
        if (b < NN) s += hist[b];
    }
    part[tid] = s;
    __syncthreads();
    if (tid == 0) {
        int a = 0;
        for (int i = 0; i < 256; ++i) { const int v = part[i]; part[i] = a; a += v; }
    }
    __syncthreads();
    int a = part[tid];
    for (int i = 0; i < 79; ++i) {
        const int b = base + i;
        if (b < NN) { offs[b] = a; a += hist[b]; }
    }
}

__global__ __launch_bounds__(256) void k_scatter(
    const int* __restrict__ src, const int* __restrict__ dst, const float* __restrict__ ed,
    int* __restrict__ offs, int* __restrict__ src_s, int* __restrict__ dst_s,
    float* __restrict__ ed_s) {
    const int e = blockIdx.x * 256 + threadIdx.x;
    const int d = dst[e];
    const int pos = atomicAdd(&offs[d], 1);
    src_s[pos] = src[e];
    dst_s[pos] = d;
    const float4 a = *(const float4*)(ed + (size_t)e * 8);
    const float4 b = *(const float4*)(ed + (size_t)e * 8 + 4);
    *(float4*)(ed_s + (size_t)pos * 8) = a;
    *(float4*)(ed_s + (size_t)pos * 8 + 4) = b;
}

// -------- h0 = x @ W_in + b_in  (+ optional bf16 hi/lo split emit)
__global__ __launch_bounds__(256) void k_input_linear(
    const float* __restrict__ x, const float* __restrict__ Win,
    const float* __restrict__ bin, float* __restrict__ h,
    unsigned short* __restrict__ hhi, unsigned short* __restrict__ hlo) {
    int idx = blockIdx.x * 256 + threadIdx.x;
    int n = idx >> 5, f = idx & 31;
    float acc = bin[f];
#pragma unroll
    for (int d = 0; d < DIN; ++d) acc += x[n * DIN + d] * Win[d * D + f];
    h[idx] = acc;
    if (hhi) {
        unsigned short hi, lo;
        split_bf16(acc, hi, lo);
        hhi[idx] = hi;
        hlo[idx] = lo;
    }
}

// -------- MFMA msg v18 (unchanged from r8; <=140us measured)
__global__ __launch_bounds__(256, 4) void k_msg_mfma18(
    const float* __restrict__ ed_s, const float* __restrict__ We1,
    const float* __restrict__ be1,
    const unsigned short* __restrict__ wth,
    const unsigned short* __restrict__ hhi,
    const int* __restrict__ src_s, const int* __restrict__ dst_s,
    float* __restrict__ agg) {
    const int tid = threadIdx.x;
    const int e0 = blockIdx.x * 256;

    __shared__ float msgb[256 * 17];  // 17408 B, epilogue only (2-pass over f)
    __shared__ float we1s[DE * HE];   // 4 KB
    __shared__ float be1s[HE];
    __shared__ int dsl[256];

    const int lane = tid & 63;
    const int wv = tid >> 6;
    const int eidx = lane & 15;
    const int quad = lane >> 4;
    const int d0 = quad * 8;
    const int swz0 = swz_off(eidx, quad, 0);
    const int swz1 = swz_off(eidx, quad, 1);

    for (int i = tid; i < DE * HE; i += 256) we1s[i] = We1[i];
    if (tid < HE) be1s[tid] = be1[tid];
    dsl[tid] = dst_s[e0 + tid];

    const float4 ev0 = *(const float4*)(ed_s + (size_t)(e0 + tid) * 8);
    const float4 ev1 = *(const float4*)(ed_s + (size_t)(e0 + tid) * 8 + 4);
    float edr[8];
    edr[0] = ev0.x; edr[1] = ev0.y; edr[2] = ev0.z; edr[3] = ev0.w;
    edr[4] = ev1.x; edr[5] = ev1.y; edr[6] = ev1.z; edr[7] = ev1.w;

    short8x bhi[4];
#pragma unroll
    for (int et = 0; et < 4; ++et) {
        const int e = e0 + wv * 64 + et * 16 + eidx;
        const size_t hb = (size_t)src_s[e] * 32 + d0;
        bhi[et] = *(const short8x*)(hhi + hb);
    }

    short8x ring[4][2];
#define LDW(slot, kk)                                                  \
    do {                                                               \
        const unsigned short* _p = wth + ((size_t)(kk) << 10);         \
        ring[slot][0] = *(const short8x*)(_p + swz0);                  \
        ring[slot][1] = *(const short8x*)(_p + swz1);                  \
    } while (0)
    LDW(0, 0);
    LDW(1, 1);
    LDW(2, 2);

    f32x4 macc[4][2];
#pragma unroll
    for (int et = 0; et < 4; ++et) {
        macc[et][0] = (f32x4){0.f, 0.f, 0.f, 0.f};
        macc[et][1] = (f32x4){0.f, 0.f, 0.f, 0.f};
    }

    __syncthreads();

#pragma unroll 1
    for (int c = 0; c < 16; ++c) {
        float zreg[8];
#pragma unroll
        for (int m = 0; m < 8; ++m) zreg[m] = be1s[c * 8 + m];
#pragma unroll
        for (int j = 0; j < 8; ++j) {
            const float4 wa = *(const float4*)&we1s[j * HE + c * 8];
            const float4 wb = *(const float4*)&we1s[j * HE + c * 8 + 4];
            const float ej = edr[j];
            zreg[0] += ej * wa.x; zreg[1] += ej * wa.y;
            zreg[2] += ej * wa.z; zreg[3] += ej * wa.w;
            zreg[4] += ej * wb.x; zreg[5] += ej * wb.y;
            zreg[6] += ej * wb.z; zreg[7] += ej * wb.w;
        }
#pragma unroll
        for (int m = 0; m < 8; ++m) zreg[m] = fmaxf(zreg[m], 0.f);

#pragma unroll
        for (int m = 0; m < 8; ++m) {
            const int k = c * 8 + m;
            const int slot = m & 3;
            const int pslot = (m + 3) & 3;
            const int kn = k + 3;  // affine: rows up to 130 exist (132 alloc'd)
            LDW(pslot, kn);

            const short8x fh0 = ring[slot][0];
            const short8x fh1 = ring[slot][1];
#pragma unroll
            for (int et = 0; et < 4; ++et) {
                const float zk = __shfl(zreg[m], et * 16 + eidx);
                f32x4 t0 = {0.f, 0.f, 0.f, 0.f}, t1 = {0.f, 0.f, 0.f, 0.f};
                t0 = __builtin_amdgcn_mfma_f32_16x16x32_bf16(fh0, bhi[et], t0, 0, 0, 0);
                t1 = __builtin_amdgcn_mfma_f32_16x16x32_bf16(fh1, bhi[et], t1, 0, 0, 0);
                macc[et][0] += zk * t0;
                macc[et][1] += zk * t1;
            }
        }
    }

    {   // k = 128: be2 virtual row, z == 1
        const short8x fh0 = ring[0][0];
        const short8x fh1 = ring[0][1];
#pragma unroll
        for (int et = 0; et < 4; ++et) {
            f32x4 t0 = {0.f, 0.f, 0.f, 0.f}, t1 = {0.f, 0.f, 0.f, 0.f};
            t0 = __builtin_amdgcn_mfma_f32_16x16x32_bf16(fh0, bhi[et], t0, 0, 0, 0);
            t1 = __builtin_amdgcn_mfma_f32_16x16x32_bf16(fh1, bhi[et], t1, 0, 0, 0);
            macc[et][0] += t0;
            macc[et][1] += t1;
        }
    }
#undef LDW

#pragma unroll
    for (int et = 0; et < 4; ++et) {
        const int eloc = wv * 64 + et * 16 + eidx;
        float* row = msgb + eloc * 17;
        row[quad * 4 + 0] = macc[et][0].x;
        row[quad * 4 + 1] = macc[et][0].y;
        row[quad * 4 + 2] = macc[et][0].z;
        row[quad * 4 + 3] = macc[et][0].w;
    }
    __syncthreads();
    {
        const int g = tid >> 4, fl = tid & 15;
        const int base = g * 16;
        float acc = 0.f;
        int cur = dsl[base];
        for (int i = 0; i < 16; ++i) {
            const int dnn = dsl[base + i];
            const float v = msgb[(base + i) * 17 + fl];
            if (dnn != cur) {
                atomicAdd(&agg[(size_t)cur * 32 + fl], acc);
                acc = 0.f;
                cur = dnn;
            }
            acc += v;
        }
        atomicAdd(&agg[(size_t)cur * 32 + fl], acc);
    }
    __syncthreads();

#pragma unroll
    for (int et = 0; et < 4; ++et) {
        const int eloc = wv * 64 + et * 16 + eidx;
        float* row = msgb + eloc * 17;
        row[quad * 4 + 0] = macc[et][1].x;
        row[quad * 4 + 1] = macc[et][1].y;
        row[quad * 4 + 2] = macc[et][1].z;
        row[quad * 4 + 3] = macc[et][1].w;
    }
    __syncthreads();
    {
        const int g = tid >> 4, fl = tid & 15;
        const int base = g * 16;
        float acc = 0.f;
        int cur = dsl[base];
        for (int i = 0; i < 16; ++i) {
            const int dnn = dsl[base + i];
            const float v = msgb[(base + i) * 17 + fl];
            if (dnn != cur) {
                atomicAdd(&agg[(size_t)cur * 32 + 16 + fl], acc);
                acc = 0.f;
                cur = dnn;
            }
            acc += v;
        }
        atomicAdd(&agg[(size_t)cur * 32 + 16 + fl], acc);
    }
}

// -------- MFMA msg v2 (fallback, base ws only)
#define LDFRAG(slot, kk)                                          \
    do {                                                          \
        const unsigned short* _ph = wth + ((size_t)(kk) << 10);   \
        const unsigned short* _pl = wtl + ((size_t)(kk) << 10);   \
        ring[slot][0] = *(const short8x*)(_ph + b0);              \
        ring[slot][1] = *(const short8x*)(_ph + b1);              \
        ring[slot][2] = *(const short8x*)(_pl + b0);              \
        ring[slot][3] = *(const short8x*)(_pl + b1);              \
    } while (0)

__global__ __launch_bounds__(256) void k_msg_mfma(
    const float* __restrict__ ed, const float* __restrict__ We1,
    const float* __restrict__ be1,
    const unsigned short* __restrict__ wth, const unsigned short* __restrict__ wtl,
    const unsigned short* __restrict__ hhi, const unsigned short* __restrict__ hlo,
    const int* __restrict__ src, const int* __restrict__ dst,
    float* __restrict__ agg) {
    const int tid = threadIdx.x;
    const int e0 = blockIdx.x * 64;

    __shared__ float we1s[DE * HE];
    __shared__ float be1s[HE];

    for (int i = tid; i < DE * HE; i += 256) we1s[i] = We1[i];
    if (tid < HE) be1s[tid] = be1[tid];

    const int lane = tid & 63;
    const int wv = tid >> 6;
    const int eidx = lane & 15;
    const int quad = lane >> 4;
    const int eloc = wv * 16 + eidx;
    const int e = e0 + eloc;
    const int d0 = quad * 8;

    const int sn = src[e];
    const int dn = dst[e];

    const int b0 = swz_off(eidx, quad, 0);
    const int b1 = swz_off(eidx, quad, 1);

    const size_t hb = (size_t)sn * 32 + d0;
    const short8x bhi = *(const short8x*)(hhi + hb);
    const short8x blo = *(const short8x*)(hlo + hb);
    const float4 edv0 = *(const float4*)(ed + (size_t)e * 8);
    const float4 edv1 = *(const float4*)(ed + (size_t)e * 8 + 4);

    short8x ring[4][4];
    LDFRAG(0, 0);
    LDFRAG(1, 1);
    LDFRAG(2, 2);

    __syncthreads();

    float edr[8];
    edr[0] = edv0.x; edr[1] = edv0.y; edr[2] = edv0.z; edr[3] = edv0.w;
    edr[4] = edv1.x; edr[5] = edv1.y; edr[6] = edv1.z; edr[7] = edv1.w;
    float zreg[32];
#pragma unroll
    for (int m = 0; m < 32; ++m) {
        const int kk = (quad << 5) + m;
        float acc = be1s[kk];
#pragma unroll
        for (int j = 0; j < 8; ++j) acc += edr[j] * we1s[j * 128 + kk];
        zreg[m] = fmaxf(acc, 0.f);
    }

    f32x4 m0 = {0.f, 0.f, 0.f, 0.f}, m1 = {0.f, 0.f, 0.f, 0.f};

    for (int q = 0; q < 4; ++q) {
        const int bsrc = q * 16 + eidx;
#pragma unroll
        for (int m = 0; m < 32; ++m) {
            const int k = q * 32 + m;
            const int slot = m & 3;
            const int pslot = (m + 3) & 3;
            int kn = k + 3;
            kn = (kn > 128) ? 128 : kn;
            LDFRAG(pslot, kn);

            const float zk = __shfl(zreg[m], bsrc);

            f32x4 t0 = {0.f, 0.f, 0.f, 0.f}, t1 = {0.f, 0.f, 0.f, 0.f};
            t0 = __builtin_amdgcn_mfma_f32_16x16x32_bf16(ring[slot][0], bhi, t0, 0, 0, 0);
            t1 = __builtin_amdgcn_mfma_f32_16x16x32_bf16(ring[slot][1], bhi, t1, 0, 0, 0);
            t0 = __builtin_amdgcn_mfma_f32_16x16x32_bf16(ring[slot][2], bhi, t0, 0, 0, 0);
            t1 = __builtin_amdgcn_mfma_f32_16x16x32_bf16(ring[slot][3], bhi, t1, 0, 0, 0);
            t0 = __builtin_amdgcn_mfma_f32_16x16x32_bf16(ring[slot][0], blo, t0, 0, 0, 0);
            t1 = __builtin_amdgcn_mfma_f32_16x16x32_bf16(ring[slot][1], blo, t1, 0, 0, 0);

            m0 += zk * t0;
            m1 += zk * t1;
        }
    }
    {
        f32x4 t0 = {0.f, 0.f, 0.f, 0.f}, t1 = {0.f, 0.f, 0.f, 0.f};
        t0 = __builtin_amdgcn_mfma_f32_16x16x32_bf16(ring[0][0], bhi, t0, 0, 0, 0);
        t1 = __builtin_amdgcn_mfma_f32_16x16x32_bf16(ring[0][1], bhi, t1, 0, 0, 0);
        t0 = __builtin_amdgcn_mfma_f32_16x16x32_bf16(ring[0][2], bhi, t0, 0, 0, 0);
        t1 = __builtin_amdgcn_mfma_f32_16x16x32_bf16(ring[0][3], bhi, t1, 0, 0, 0);
        t0 = __builtin_amdgcn_mfma_f32_16x16x32_bf16(ring[0][0], blo, t0, 0, 0, 0);
        t1 = __builtin_amdgcn_mfma_f32_16x16x32_bf16(ring[0][1], blo, t1, 0, 0, 0);
        m0 += t0;
        m1 += t1;
    }

    float* ap = agg + (size_t)dn * 32 + quad * 4;
    atomicAdd(ap + 0, m0.x);
    atomicAdd(ap + 1, m0.y);
    atomicAdd(ap + 2, m0.z);
    atomicAdd(ap + 3, m0.w);
    atomicAdd(ap + 16 + 0, m1.x);
    atomicAdd(ap + 16 + 1, m1.y);
    atomicAdd(ap + 16 + 2, m1.z);
    atomicAdd(ap + 16 + 3, m1.w);
}

// -------- fallback (base ws): recompute z per edge, fp32 VALU bilinear
__global__ __launch_bounds__(256) void k_msg_fused(
    const float* __restrict__ ed, const float* __restrict__ We1,
    const float* __restrict__ be1, const float* __restrict__ We2,
    const float* __restrict__ h, const int* __restrict__ src,
    const int* __restrict__ dst, float* __restrict__ agg) {
    const int tid = threadIdx.x;
    const int e0 = blockIdx.x * 64;
    __shared__ float we1s[DE * HE];
    __shared__ float be1s[HE];
    __shared__ float eds[64][9];
    __shared__ float zs[HE][64];
    __shared__ float hs[64][33];
    __shared__ float ws2s[4][1024];
    __shared__ int srcs[64];

    for (int i = tid; i < DE * HE; i += 256) we1s[i] = We1[i];
    if (tid < HE) be1s[tid] = be1[tid];
    if (tid < 64) srcs[tid] = src[e0 + tid];
    for (int i = tid; i < 64 * DE; i += 256) eds[i >> 3][i & 7] = ed[(size_t)e0 * DE + i];
    __syncthreads();

    {
        const int e = tid & 63, kb = tid >> 6;
        float edr[8];
#pragma unroll
        for (int j = 0; j < 8; ++j) edr[j] = eds[e][j];
        for (int m = 0; m < 32; ++m) {
            const int k = kb * 32 + m;
            float acc = be1s[k];
#pragma unroll
            for (int j = 0; j < 8; ++j) acc += edr[j] * we1s[j * HE + k];
            zs[k][e] = fmaxf(acc, 0.f);
        }
    }
    for (int i = tid; i < 64 * 32; i += 256) {
        const int e = i >> 5, d = i & 31;
        hs[e][d] = h[(size_t)srcs[e] * D + d];
    }
    __syncthreads();

    const int ep = tid & 31, fg = tid >> 5;
    float hr[2][32];
#pragma unroll
    for (int d = 0; d < 32; ++d) {
        hr[0][d] = hs[ep * 2][d];
        hr[1][d] = hs[ep * 2 + 1][d];
    }
    float acc[2][4];
#pragma unroll
    for (int i = 0; i < 2; ++i)
#pragma unroll
        for (int j = 0; j < 4; ++j) acc[i][j] = 0.f;

    for (int kc = 0; kc < 32; ++kc) {
        __syncthreads();
#pragma unroll
        for (int r = 0; r < 4; ++r) {
            const int idx4 = tid + 256 * r;
            const int kr = idx4 >> 8, c4 = idx4 & 255;
            *(float4*)&ws2s[kr][c4 * 4] =
                *(const float4*)(We2 + (size_t)(kc * 4 + kr) * 1024 + c4 * 4);
        }
        __syncthreads();
#pragma unroll
        for (int kk = 0; kk < 4; ++kk) {
            const int k = kc * 4 + kk;
            const float z0 = zs[k][ep * 2], z1 = zs[k][ep * 2 + 1];
#pragma unroll
            for (int d = 0; d < 32; ++d) {
                const float4 w4 = *(const float4*)&ws2s[kk][d * 32 + fg * 4];
                const float c0 = z0 * hr[0][d], c1 = z1 * hr[1][d];
                acc[0][0] += c0 * w4.x; acc[0][1] += c0 * w4.y;
                acc[0][2] += c0 * w4.z; acc[0][3] += c0 * w4.w;
                acc[1][0] += c1 * w4.x; acc[1][1] += c1 * w4.y;
                acc[1][2] += c1 * w4.z; acc[1][3] += c1 * w4.w;
            }
        }
    }
#pragma unroll
    for (int i = 0; i < 2; ++i) {
        const int e = e0 + ep * 2 + i;
        float* ap = &agg[(size_t)dst[e] * D + fg * 4];
#pragma unroll
        for (int j = 0; j < 4; ++j) atomicAdd(ap + j, acc[i][j]);
    }
}

// -------- GRU v19: transposed-coalesced weight reads (bit-identical math)
__global__ __launch_bounds__(256) void k_gru(
    const float* __restrict__ h, float* __restrict__ agg,
    const float* __restrict__ Wroot, const float* __restrict__ bconv,
    const float* __restrict__ WihT, const float* __restrict__ WhhT,
    const float* __restrict__ bih, const float* __restrict__ bhh,
    float* __restrict__ hout,
    unsigned short* __restrict__ hhi, unsigned short* __restrict__ hlo) {
    const int idx = blockIdx.x * 256 + threadIdx.x;
    const int n = idx >> 5, f = idx & 31, nl = threadIdx.x >> 5;
    __shared__ float hsh[8][33], msh[8][33];
    const float hv = h[n * D + f];
    hsh[nl][f] = hv;
    __syncthreads();
    float m = bconv[f] + agg[n * D + f];
    agg[n * D + f] = 0.f;  // re-zero for next msg step
#pragma unroll
    for (int d = 0; d < 32; ++d) m += hsh[nl][d] * Wroot[d * D + f];
    m = fmaxf(m, 0.f);
    msh[nl][f] = m;
    __syncthreads();
    float gir = bih[f], giz = bih[D + f], gin = bih[2 * D + f];
    float ghr = bhh[f], ghz = bhh[D + f], ghn = bhh[2 * D + f];
#pragma unroll
    for (int d = 0; d < 32; ++d) {
        const float md = msh[nl][d], hd = hsh[nl][d];
        gir += md * WihT[d * 96 + f];
        giz += md * WihT[d * 96 + 32 + f];
        gin += md * WihT[d * 96 + 64 + f];
        ghr += hd * WhhT[d * 96 + f];
        ghz += hd * WhhT[d * 96 + 32 + f];
        ghn += hd * WhhT[d * 96 + 64 + f];
    }
    const float r = sigf(gir + ghr);
    const float z = sigf(giz + ghz);
    const float nn2 = tanhf(gin + r * ghn);
    const float ho = (1.f - z) * nn2 + z * hv;
    hout[n * D + f] = ho;
    if (hhi) {
        unsigned short hi, lo;
        split_bf16(ho, hi, lo);
        hhi[idx] = hi;
        hlo[idx] = lo;
    }
}

// -------- GRU fallback (original global weight reads)
__global__ __launch_bounds__(256) void k_gru_fb(
    const float* __restrict__ h, float* __restrict__ agg,
    const float* __restrict__ Wroot, const float* __restrict__ bconv,
    const float* __restrict__ Wih, const float* __restrict__ Whh,
    const float* __restrict__ bih, const float* __restrict__ bhh,
    float* __restrict__ hout,
    unsigned short* __restrict__ hhi, unsigned short* __restrict__ hlo) {
    const int idx = blockIdx.x * 256 + threadIdx.x;
    const int n = idx >> 5, f = idx & 31, nl = threadIdx.x >> 5;
    __shared__ float hsh[8][33], msh[8][33];
    const float hv = h[n * D + f];
    hsh[nl][f] = hv;
    __syncthreads();
    float m = bconv[f] + agg[n * D + f];
    agg[n * D + f] = 0.f;
#pragma unroll
    for (int d = 0; d < 32; ++d) m += hsh[nl][d] * Wroot[d * D + f];
    m = fmaxf(m, 0.f);
    msh[nl][f] = m;
    __syncthreads();
    float gir = bih[f], giz = bih[D + f], gin = bih[2 * D + f];
    float ghr = bhh[f], ghz = bhh[D + f], ghn = bhh[2 * D + f];
#pragma unroll
    for (int d = 0; d < 32; ++d) {
        const float md = msh[nl][d], hd = hsh[nl][d];
        gir += md * Wih[f * D + d];
        giz += md * Wih[(D + f) * D + d];
        gin += md * Wih[(2 * D + f) * D + d];
        ghr += hd * Whh[f * D + d];
        ghz += hd * Whh[(D + f) * D + d];
        ghn += hd * Whh[(2 * D + f) * D + d];
    }
    const float r = sigf(gir + ghr);
    const float z = sigf(giz + ghz);
    const float nn2 = tanhf(gin + r * ghn);
    const float ho = (1.f - z) * nn2 + z * hv;
    hout[n * D + f] = ho;
    if (hhi) {
        unsigned short hi, lo;
        split_bf16(ho, hi, lo);
        hhi[idx] = hi;
        hlo[idx] = lo;
    }
}

// -------- Set2Set v19: coalesced transposed gates weights, h-slice + attn
// weights in LDS, wave-butterfly reductions (23 -> 6 barriers/step).
__global__ __launch_bounds__(256) void k_s2s_all(
    const float* __restrict__ h, const int* __restrict__ batch,
    const float* __restrict__ WihT, const float* __restrict__ WhhT,
    const float* __restrict__ bih, const float* __restrict__ bhh,
    const float* __restrict__ Wout, const float* __restrict__ bout,
    float* __restrict__ ebuf, float* __restrict__ out) {
    const int b = blockIdx.x, t = threadIdx.x;
    __shared__ float qst[64], hls[32], cls[32], gates[128], qs[32];
    __shared__ float red4m[4], red4s[4];
    __shared__ float rsum[8][33];
    __shared__ float wls[512];
    __shared__ float hcache[512 * 33];  // 67.6 KB
    __shared__ int sse[2];
    if (t < 64) qst[t] = 0.f;
    if (t < 32) { hls[t] = 0.f; cls[t] = 0.f; }
    if (t < 2) {  // own graph segment via binary search on sorted batch
        const int target = b + t;
        int lo = 0, hi = NN;
        while (lo < hi) {
            int mid = (lo + hi) >> 1;
            if (batch[mid] < target) lo = mid + 1; else hi = mid;
        }
        sse[t] = lo;
    }
    __syncthreads();
    const int s0 = sse[0], s1 = sse[1];
    const int seg = s1 - s0;
    const bool fit = seg <= 512;
    if (fit) {  // stage h slice once (padded 33: conflict-free scalar reads)
        for (int i = t; i < seg * 32; i += 256)
            hcache[(i >> 5) * 33 + (i & 31)] = h[(size_t)s0 * 32 + i];
    }
    __syncthreads();
    const int wv = t >> 6;

    for (int s = 0; s < S2S; ++s) {
        if (t < 128) {
            float g = bih[t] + bhh[t];
#pragma unroll 8
            for (int j = 0; j < 64; ++j) g += qst[j] * WihT[j * 128 + t];
#pragma unroll 8
            for (int j = 0; j < 32; ++j) g += hls[j] * WhhT[j * 128 + t];
            gates[t] = g;
        }
        __syncthreads();  // B1
        if (t < 32) {  // i,f,g,o order
            const float ig = sigf(gates[t]);
            const float fg = sigf(gates[32 + t]);
            const float gg = tanhf(gates[64 + t]);
            const float og = sigf(gates[96 + t]);
            const float c = fg * cls[t] + ig * gg;
            const float q = og * tanhf(c);
            cls[t] = c;
            hls[t] = q;
            qst[t] = q;
            qs[t] = q;
        }
        __syncthreads();  // B2
        float lmax = -3.4e38f;
        for (int n = s0 + t; n < s1; n += 256) {
            const int nn = n - s0;
            float e = 0.f;
            if (fit) {
#pragma unroll
                for (int d = 0; d < 32; ++d) e += hcache[nn * 33 + d] * qs[d];
                wls[nn] = e;
            } else {
                const float4* hv = (const float4*)(h + (size_t)n * D);
#pragma unroll
                for (int u = 0; u < 8; ++u) {
                    const float4 v = hv[u];
                    e += v.x * qs[u * 4] + v.y * qs[u * 4 + 1] + v.z * qs[u * 4 + 2] + v.w * qs[u * 4 + 3];
                }
                ebuf[n] = e;
            }
            lmax = fmaxf(lmax, e);
        }
#pragma unroll
        for (int off = 32; off > 0; off >>= 1) lmax = fmaxf(lmax, __shfl_xor(lmax, off));
        if ((t & 63) == 0) red4m[wv] = lmax;
        __syncthreads();  // B3
        const float smax = fmaxf(fmaxf(red4m[0], red4m[1]), fmaxf(red4m[2], red4m[3]));
        float lsum = 0.f;
        for (int n = s0 + t; n < s1; n += 256) {
            const int nn = n - s0;
            const float ev = fit ? wls[nn] : ebuf[n];
            const float w = expf(ev - smax);
            if (fit) wls[nn] = w; else ebuf[n] = w;
            lsum += w;
        }
#pragma unroll
        for (int off = 32; off > 0; off >>= 1) lsum += __shfl_xor(lsum, off);
        if ((t & 63) == 0) red4s[wv] = lsum;
        __syncthreads();  // B4
        const float den = red4s[0] + red4s[1] + red4s[2] + red4s[3];
        const float inv = (den > 0.f) ? 1.f / den : 0.f;
        const int fl = t & 31, sl = t >> 5;
        float racc = 0.f;
        if (fit) {
            for (int nn = sl; nn < seg; nn += 8) racc += wls[nn] * hcache[nn * 33 + fl];
        } else {
            for (int n = s0 + sl; n < s1; n += 8) racc += ebuf[n] * h[(size_t)n * D + fl];
        }
        rsum[sl][fl] = racc;
        __syncthreads();  // B5
        if (sl == 0) {
            float rv = 0.f;
#pragma unroll
            for (int u = 0; u < 8; ++u) rv += rsum[u][fl];
            qst[32 + fl] = rv * inv;
        }
        __syncthreads();  // B6
    }

    if (t == 0) {  // fused output head
        float acc = bout[0];
#pragma unroll 8
        for (int j = 0; j < 64; ++j) acc += qst[j] * Wout[j];
        out[b] = acc;
    }
}

// -------- Set2Set fallback (original, global weights + ebuf)
__global__ __launch_bounds__(256) void k_s2s_fb(
    const float* __restrict__ h, const int* __restrict__ batch,
    const float* __restrict__ Wih, const float* __restrict__ Whh,
    const float* __restrict__ bih, const float* __restrict__ bhh,
    const float* __restrict__ Wout, const float* __restrict__ bout,
    float* __restrict__ ebuf, float* __restrict__ out) {
    const int b = blockIdx.x, t = threadIdx.x;
    __shared__ float qst[64], hls[32], cls[32], gates[128], qs[32];
    __shared__ float red[256];
    __shared__ float rsum[8][33];
    __shared__ int sse[2];
    if (t < 64) qst[t] = 0.f;
    if (t < 32) { hls[t] = 0.f; cls[t] = 0.f; }
    if (t < 2) {
        const int target = b + t;
        int lo = 0, hi = NN;
        while (lo < hi) {
            int mid = (lo + hi) >> 1;
            if (batch[mid] < target) lo = mid + 1; else hi = mid;
        }
        sse[t] = lo;
    }
    __syncthreads();
    const int s0 = sse[0], s1 = sse[1];

    for (int s = 0; s < S2S; ++s) {
        if (t < 128) {
            float g = bih[t] + bhh[t];
#pragma unroll 8
            for (int j = 0; j < 64; ++j) g += qst[j] * Wih[t * 64 + j];
#pragma unroll 8
            for (int j = 0; j < 32; ++j) g += hls[j] * Whh[t * 32 + j];
            gates[t] = g;
        }
        __syncthreads();
        if (t < 32) {
            const float ig = sigf(gates[t]);
            const float fg = sigf(gates[32 + t]);
            const float gg = tanhf(gates[64 + t]);
            const float og = sigf(gates[96 + t]);
            const float c = fg * cls[t] + ig * gg;
            const float q = og * tanhf(c);
            cls[t] = c;
            hls[t] = q;
            qst[t] = q;
            qs[t] = q;
        }
        __syncthreads();
        float lmax = -3.4e38f;
        for (int n = s0 + t; n < s1; n += 256) {
            const float4* hv = (const float4*)(h + (size_t)n * D);
            float e = 0.f;
#pragma unroll
            for (int u = 0; u < 8; ++u) {
                const float4 v = hv[u];
                e += v.x * qs[u * 4] + v.y * qs[u * 4 + 1] + v.z * qs[u * 4 + 2] + v.w * qs[u * 4 + 3];
            }
            ebuf[n] = e;
            lmax = fmaxf(lmax, e);
        }
        red[t] = lmax;
        __syncthreads();
        for (int r2 = 128; r2 > 0; r2 >>= 1) {
            if (t < r2) red[t] = fmaxf(red[t], red[t + r2]);
            __syncthreads();
        }
        const float smax = red[0];
        __syncthreads();
        float lsum = 0.f;
        for (int n = s0 + t; n < s1; n += 256) {
            const float w = expf(ebuf[n] - smax);
            ebuf[n] = w;
            lsum += w;
        }
        red[t] = lsum;
        __syncthreads();
        for (int r2 = 128; r2 > 0; r2 >>= 1) {
            if (t < r2) red[t] += red[t + r2];
            __syncthreads();
        }
        const float den = red[0];
        const float inv = (den > 0.f) ? 1.f / den : 0.f;
        const int fl = t & 31, sl = t >> 5;
        float racc = 0.f;
        for (int n = s0 + sl; n < s1; n += 8) racc += ebuf[n] * h[(size_t)n * D + fl];
        rsum[sl][fl] = racc;
        __syncthreads();
        if (sl == 0) {
            float rv = 0.f;
#pragma unroll
            for (int u = 0; u < 8; ++u) rv += rsum[u][fl];
            qst[32 + fl] = rv * inv;
        }
        __syncthreads();
    }

    if (t == 0) {
        float acc = bout[0];
#pragma unroll 8
        for (int j = 0; j < 64; ++j) acc += qst[j] * Wout[j];
        out[b] = acc;
    }
}

extern "C" void kernel_launch(void* const* d_in, const int* in_sizes, int n_in,
                              void* d_out, int out_size, void* d_ws, size_t ws_size,
                              hipStream_t stream) {
    const float* x     = (const float*)d_in[0];
    const float* ed    = (const float*)d_in[3];
    const int*   edges = (const int*)d_in[4];
    const int*   batch = (const int*)d_in[5];
    const float* Wi    = (const float*)d_in[6];
    const float* bi    = (const float*)d_in[7];
    const float* We1   = (const float*)d_in[8];
    const float* be1   = (const float*)d_in[9];
    const float* We2   = (const float*)d_in[10];
    const float* be2   = (const float*)d_in[11];
    const float* Wroot = (const float*)d_in[12];
    const float* bconv = (const float*)d_in[13];
    const float* gWih  = (const float*)d_in[14];
    const float* gWhh  = (const float*)d_in[15];
    const float* gbih  = (const float*)d_in[16];
    const float* gbhh  = (const float*)d_in[17];
    const float* lWih  = (const float*)d_in[18];
    const float* lWhh  = (const float*)d_in[19];
    const float* lbih  = (const float*)d_in[20];
    const float* lbhh  = (const float*)d_in[21];
    const float* Wout  = (const float*)d_in[22];
    const float* bout  = (const float*)d_in[23];
    float* out = (float*)d_out;

    const int* srcp = edges;
    const int* dstp = edges + NE;

    char* ws = (char*)d_ws;
    size_t off = 0;
    auto alloc = [&](size_t bytes) -> char* {
        char* p = ws + off;
        off += (bytes + 255) & ~(size_t)255;
        return p;
    };
    float* hA    = (float*)alloc((size_t)NN * D * 4);
    float* hB    = (float*)alloc((size_t)NN * D * 4);
    float* agg   = (float*)alloc((size_t)NN * D * 4);
    float* ebuf  = (float*)alloc((size_t)NN * 4);
    unsigned short* hhiA = (unsigned short*)alloc((size_t)NN * D * 2);
    unsigned short* hloA = (unsigned short*)alloc((size_t)NN * D * 2);
    unsigned short* hhiB = (unsigned short*)alloc((size_t)NN * D * 2);
    unsigned short* hloB = (unsigned short*)alloc((size_t)NN * D * 2);
    // wth: 132 rows (129 real + 3 overrun rows read into dead ring slots)
    unsigned short* wth  = (unsigned short*)alloc((size_t)132 * 1024 * 2);
    unsigned short* wtl  = (unsigned short*)alloc((size_t)129 * 1024 * 2);
    const size_t base_off = off;
    const bool mfma_path = (ws_size >= base_off);
    // transposed weight copies (~96 KB)
    float* gWihT = (float*)alloc((size_t)32 * 96 * 4);
    float* gWhhT = (float*)alloc((size_t)32 * 96 * 4);
    float* lWihT = (float*)alloc((size_t)64 * 128 * 4);
    float* lWhhT = (float*)alloc((size_t)32 * 128 * 4);
    const size_t trans_off = off;
    const bool trans_path = (ws_size >= trans_off);
    // sorted-edge extras (~14 MB)
    int*   hist  = (int*)alloc((size_t)NN * 4);
    int*   offs  = (int*)alloc((size_t)NN * 4);
    int*   src_s = (int*)alloc((size_t)NE * 4);
    int*   dst_s = (int*)alloc((size_t)NE * 4);
    float* ed_s  = (float*)alloc((size_t)NE * 8 * 4);
    const bool mfma10_path = (ws_size >= off);

    hipLaunchKernelGGL(k_input_linear, dim3(NN * D / 256), dim3(256), 0, stream, x, Wi, bi, hA,
                       mfma_path ? hhiA : (unsigned short*)nullptr,
                       mfma_path ? hloA : (unsigned short*)nullptr);
    if (mfma_path)
        hipLaunchKernelGGL(k_prep_w, dim3((129 * 1024 + 255) / 256), dim3(256), 0, stream,
                           We2, be2, wth, wtl);
    if (trans_path)
        hipLaunchKernelGGL(k_prep_t, dim3((18432 + 255) / 256), dim3(256), 0, stream,
                           gWih, gWhh, lWih, lWhh, gWihT, gWhhT, lWihT, lWhhT);
    if (mfma10_path) {
        hipMemsetAsync(hist, 0, (size_t)NN * 4, stream);
        hipLaunchKernelGGL(k_hist, dim3(NE / 256), dim3(256), 0, stream, dstp, hist);
        hipLaunchKernelGGL(k_scan, dim3(1), dim3(256), 0, stream, hist, offs);
        hipLaunchKernelGGL(k_scatter, dim3(NE / 256), dim3(256), 0, stream,
                           srcp, dstp, ed, offs, src_s, dst_s, ed_s);
    }
    hipMemsetAsync(agg, 0, (size_t)NN * D * 4, stream);  // once; k_gru re-zeroes

    float* hcur = hA;
    float* hnxt = hB;
    unsigned short *hhic = hhiA, *hloc = hloA, *hhin = hhiB, *hlon = hloB;
    for (int t = 0; t < TST; ++t) {
        if (mfma10_path)
            hipLaunchKernelGGL(k_msg_mfma18, dim3(NE / 256), dim3(256), 0, stream,
                               ed_s, We1, be1, wth, hhic, src_s, dst_s, agg);
        else if (mfma_path)
            hipLaunchKernelGGL(k_msg_mfma, dim3(NE / 64), dim3(256), 0, stream,
                               ed, We1, be1, wth, wtl, hhic, hloc, srcp, dstp, agg);
        else
            hipLaunchKernelGGL(k_msg_fused, dim3(NE / 64), dim3(256), 0, stream,
                               ed, We1, be1, We2, hcur, srcp, dstp, agg);
        if (trans_path)
            hipLaunchKernelGGL(k_gru, dim3(NN * D / 256), dim3(256), 0, stream,
                               hcur, agg, Wroot, bconv, gWihT, gWhhT, gbih, gbhh, hnxt,
                               mfma_path ? hhin : (unsigned short*)nullptr,
                               mfma_path ? hlon : (unsigned short*)nullptr);
        else
            hipLaunchKernelGGL(k_gru_fb, dim3(NN * D / 256), dim3(256), 0, stream,
                               hcur, agg, Wroot, bconv, gWih, gWhh, gbih, gbhh, hnxt,
                               mfma_path ? hhin : (unsigned short*)nullptr,
                               mfma_path ? hlon : (unsigned short*)nullptr);
        float* tf = hcur; hcur = hnxt; hnxt = tf;
        unsigned short* ts;
        ts = hhic; hhic = hhin; hhin = ts;
        ts = hloc; hloc = hlon; hlon = ts;
    }

    if (trans_path)
        hipLaunchKernelGGL(k_s2s_all, dim3(NB), dim3(256), 0, stream,
                           hcur, batch, lWihT, lWhhT, lbih, lbhh, Wout, bout, ebuf, out);
    else
        hipLaunchKernelGGL(k_s2s_fb, dim3(NB), dim3(256), 0, stream,
                           hcur, batch, lWih, lWhh, lbih, lbhh, Wout, bout, ebuf, out);
    (void)in_sizes; (void)n_in; (void)out_size;
}